// Round 11
// baseline (371.602 us; speedup 1.0000x reference)
//
#include <hip/hip_runtime.h>
#include <hip/hip_bf16.h>
#include <cstdint>
#include <cstddef>

typedef __bf16 bf16_t;
typedef bf16_t bf16x4 __attribute__((ext_vector_type(4)));
typedef bf16_t bf16x8 __attribute__((ext_vector_type(8)));
typedef float f32x4 __attribute__((ext_vector_type(4)));

static constexpr int NROWS = 16384;
static constexpr int CDIM  = 1024;

// ---------------- K-permutation (contiguous MFMA fragments) ----------------
// p6: k=[b5 b4 b3 b2 b1 b0] -> s=[b5 b3 b2 b4 b1 b0]; maps {0..31}->{0..31};
// preserves k&3. Fragment (ks,g) = storage elems [ks*32+8g .. +7] (16B).
__device__ __forceinline__ int p6(int k) {
  return (k & 32) | ((k & 12) << 1) | ((k & 16) >> 2) | (k & 3);
}
__device__ __forceinline__ int p6i(int s) {
  return (s & 32) | ((s & 4) << 2) | ((s & 24) >> 1) | (s & 3);
}
__device__ __forceinline__ int permc(int c) {        // within-64 perm of a wider index
  return (c & ~63) | p6(c & 63);
}

// ---------------- helpers ----------------

__device__ __forceinline__ void gload16(const bf16_t* g, bf16_t* l) {
  __builtin_amdgcn_global_load_lds((const __attribute__((address_space(1))) void*)g,
                                   (__attribute__((address_space(3))) void*)l, 16, 0, 0);
}

// Single-b128 fragment load from a row-major LDS tile whose 16B granules are
// XOR-swizzled: granule byte-addr ^= (row&7)<<4. kbyte is a multiple of 16.
__device__ __forceinline__ bf16x8 ldsf128(const bf16_t* lds, int row, int ldbytes, int kbyte) {
  const char* p = (const char*)lds + row * ldbytes + (kbyte ^ ((row & 7) << 4));
  return *(const bf16x8*)p;
}

__device__ __forceinline__ float phi_fn(float v) {           // elu + 1
  return v > 0.f ? v + 1.f : expf(v);
}
__device__ __forceinline__ float gelu_fn(float v) {          // exact gelu
  return 0.5f * v * (1.f + erff(v * 0.70710678118654752f));
}

// ---------------- elementwise / prep ----------------

// xb[row][PERM(c)] = (bf16) x[row][c]  -- written chunk-wise (8 elems/chunk).
__global__ void cast_x_kernel(const float* __restrict__ x, bf16_t* __restrict__ xb, long nchunks) {
  long i = (long)blockIdx.x * blockDim.x + threadIdx.x;
  long stride = (long)gridDim.x * blockDim.x;
  for (long c = i; c < nchunks; c += stride) {
    long row = c >> 7;
    int p0 = (int)(c & 127) << 3;            // storage position of this 8-elem chunk
    int group = p0 & ~63;
    int ccl = (p0 >> 3) & 7;                 // chunk within 64-group
    int klo = ((ccl & 4) << 3) | ((ccl & 3) << 2);   // logical k of elems 0-3 (4-7 = +16)
    const float* src = x + row * 1024 + group + klo;
    float4 a = *(const float4*)src;
    float4 b = *(const float4*)(src + 16);
    bf16x8 o;
    o[0] = (bf16_t)a.x; o[1] = (bf16_t)a.y; o[2] = (bf16_t)a.z; o[3] = (bf16_t)a.w;
    o[4] = (bf16_t)b.x; o[5] = (bf16_t)b.y; o[6] = (bf16_t)b.z; o[7] = (bf16_t)b.w;
    *(bf16x8*)(xb + row * 1024 + p0) = o;
  }
}

// Transpose-cast weights to column-major bf16 (Bt[n][k_perm]); modes 0-2 also
// apply the head-major column permutation perm(c) = (c%8)*128 + c/8.
__global__ void prep_w_kernel(const float* __restrict__ Wq, const float* __restrict__ Wkv,
                              const float* __restrict__ W1, const float* __restrict__ W2,
                              bf16_t* __restrict__ wqkv_bt, bf16_t* __restrict__ w1bt,
                              bf16_t* __restrict__ w2bt) {
  __shared__ float tile[64][65];
  int mode = blockIdx.z;
  const float* src; int ld; bf16_t* dst; int permute;
  if (mode == 0)      { src = Wq;          ld = 1024; dst = wqkv_bt;                       permute = 1; }
  else if (mode == 1) { src = Wkv;         ld = 2048; dst = wqkv_bt + (size_t)1024 * 1024; permute = 1; }
  else if (mode == 2) { src = Wkv + 1024;  ld = 2048; dst = wqkv_bt + (size_t)2048 * 1024; permute = 1; }
  else if (mode == 3) { src = W1;          ld = 1024; dst = w1bt;                          permute = 0; }
  else                { src = W2;          ld = 1024; dst = w2bt;                          permute = 0; }
  int r0 = blockIdx.x * 64, c0 = blockIdx.y * 64;
  int tid = threadIdx.x;
#pragma unroll
  for (int i = 0; i < 16; i++) {
    int idx = i * 256 + tid; int rr = idx >> 6, cc = idx & 63;
    tile[rr][cc] = src[(size_t)(r0 + rr) * ld + c0 + cc];
  }
  __syncthreads();
#pragma unroll
  for (int i = 0; i < 16; i++) {
    int idx = i * 256 + tid; int cc = idx >> 6, rr = idx & 63;
    int c = c0 + cc;
    int a = permute ? (((c & 7) << 7) | (c >> 3)) : c;
    dst[(size_t)a * 1024 + r0 + p6(rr)] = (bf16_t)tile[rr][cc];
  }
}

// ---------------- main GEMM: 256x256 tile, BK=32, fine-phase ring pipeline ---
// out = A[M][Kp] @ Bt[N][Kp]^T, K=1024 (32 K-tiles). 8 waves (2Mx4N), 512T,
// per-wave output 128x64 (acc[8][4]). LDS = 4 ring slots x 32KB (A 8K + B 8K
// elems, fragment-blocked: block bi = 16 rows, granule (l15,g) at bi*512+lane*8
// so every fragment read = base + lane*16B, conflict-free).
// Schedule per K-tile t (compute slot t&3, stage tile t+2 into slot (t+2)&3,
// which was last read at tile t-2 -> no WAR):
//   phase 1: issue 2 gloads (A of t+2); 8 ds_read; barrier; 16 MFMA (ih0); barrier
//   phase 2: issue 2 gloads (B of t+2); 8 ds_read; 16 MFMA (ih1);
//            vmcnt(4) [t+1's A+B = 4 oldest per-wave loads landed]; barrier
// vmcnt never 0 until drain (t=30). Barrier after vmcnt makes it block-wide.

template<int MODE>
__global__ __launch_bounds__(512, 1)
void gemm8p_kernel(const bf16_t* __restrict__ A, const bf16_t* __restrict__ Bt,
                   const float* __restrict__ bias,
                   bf16_t* __restrict__ o0, bf16_t* __restrict__ o1, bf16_t* __restrict__ o2,
                   int tn_count)
{
  __shared__ bf16_t lds[4 * 16384];          // 128 KB
  const int tid = threadIdx.x, lane = tid & 63, wave = tid >> 6;
  const int l15 = lane & 15, g = lane >> 4;
  const int cpx = gridDim.x >> 3;            // XCD-aware bijective swizzle (grid%8==0)
  int swz = (blockIdx.x & 7) * cpx + (blockIdx.x >> 3);
  const int row0 = (swz / tn_count) * 256, col0 = (swz % tn_count) * 256;
  const int wrb = (wave >> 2) * 8, wcb = (wave & 3) * 4;   // fragment-block bases
  f32x4 acc[8][4] = {};

  const size_t aoff0 = (size_t)(row0 + wave * 16 + l15) * 1024 + g * 8;
  const size_t aoff1 = aoff0 + (size_t)128 * 1024;
  const size_t boff0 = (size_t)(col0 + wave * 16 + l15) * 1024 + g * 8;
  const size_t boff1 = boff0 + (size_t)128 * 1024;
  const int wd0 = wave * 512, wd1 = (wave + 8) * 512;

  auto stageA = [&](int t) {
    bf16_t* s = lds + (t & 3) * 16384;
    gload16(A + aoff0 + t * 32, s + wd0);
    gload16(A + aoff1 + t * 32, s + wd1);
  };
  auto stageB = [&](int t) {
    bf16_t* s = lds + (t & 3) * 16384 + 8192;
    gload16(Bt + boff0 + t * 32, s + wd0);
    gload16(Bt + boff1 + t * 32, s + wd1);
  };

  stageA(0); stageB(0); stageA(1); stageB(1);
  asm volatile("s_waitcnt vmcnt(4)" ::: "memory");   // tile 0 landed (per-wave)
  __builtin_amdgcn_sched_barrier(0);
  __builtin_amdgcn_s_barrier();                      // block-wide
  __builtin_amdgcn_sched_barrier(0);

  for (int t = 0; t < 32; ++t) {
    const bf16_t* sA = lds + (t & 3) * 16384;
    const bf16_t* sB = sA + 8192;

    // ---- phase 1: stage A(t+2); compute quadrant ih0 ----
    if (t < 30) stageA(t + 2);
    {
      bf16x8 af[4], bfr[4];
#pragma unroll
      for (int i = 0; i < 4; i++) af[i]  = *(const bf16x8*)(sA + (wrb + i) * 512 + lane * 8);
#pragma unroll
      for (int j = 0; j < 4; j++) bfr[j] = *(const bf16x8*)(sB + (wcb + j) * 512 + lane * 8);
      __builtin_amdgcn_sched_barrier(0);
      __builtin_amdgcn_s_barrier();
      __builtin_amdgcn_sched_barrier(0);
      __builtin_amdgcn_s_setprio(1);
#pragma unroll
      for (int i = 0; i < 4; i++)
#pragma unroll
        for (int j = 0; j < 4; j++)
          acc[i][j] = __builtin_amdgcn_mfma_f32_16x16x32_bf16(af[i], bfr[j], acc[i][j], 0, 0, 0);
      __builtin_amdgcn_s_setprio(0);
    }
    __builtin_amdgcn_sched_barrier(0);
    __builtin_amdgcn_s_barrier();
    __builtin_amdgcn_sched_barrier(0);

    // ---- phase 2: stage B(t+2); compute quadrant ih1 ----
    if (t < 30) stageB(t + 2);
    {
      bf16x8 af[4], bfr[4];
#pragma unroll
      for (int i = 0; i < 4; i++) af[i]  = *(const bf16x8*)(sA + (wrb + 4 + i) * 512 + lane * 8);
#pragma unroll
      for (int j = 0; j < 4; j++) bfr[j] = *(const bf16x8*)(sB + (wcb + j) * 512 + lane * 8);
      __builtin_amdgcn_sched_barrier(0);
      __builtin_amdgcn_s_barrier();
      __builtin_amdgcn_sched_barrier(0);
      __builtin_amdgcn_s_setprio(1);
#pragma unroll
      for (int i = 0; i < 4; i++)
#pragma unroll
        for (int j = 0; j < 4; j++)
          acc[4 + i][j] = __builtin_amdgcn_mfma_f32_16x16x32_bf16(af[i], bfr[j], acc[4 + i][j], 0, 0, 0);
      __builtin_amdgcn_s_setprio(0);
    }
    // end of tile: counted wait for tile t+1; keep t+2 in flight
    if (t < 30)       asm volatile("s_waitcnt vmcnt(4)" ::: "memory");
    else if (t == 30) asm volatile("s_waitcnt vmcnt(0)" ::: "memory");
    __builtin_amdgcn_sched_barrier(0);
    __builtin_amdgcn_s_barrier();
    __builtin_amdgcn_sched_barrier(0);
  }

  // epilogue: D col = l&15, row = 4*(lane>>4) + reg
#pragma unroll
  for (int i = 0; i < 8; i++) {
    int rbase = row0 + (wave >> 2) * 128 + i * 16 + g * 4;
#pragma unroll
    for (int j = 0; j < 4; j++) {
      int col = col0 + (wave & 3) * 64 + j * 16 + l15;
      f32x4 v = acc[i][j];
      if constexpr (MODE == 0) {
        int seg = col >> 10;
        int f   = col & 1023;                // head-major feature
        if (seg == 0) {
          int cl = permc(f);                 // phiq: [n][f_perm] (attn's k-dim)
#pragma unroll
          for (int rr = 0; rr < 4; rr++)
            o0[(size_t)(rbase + rr) * 1024 + cl] = (bf16_t)phi_fn(v[rr]);
        } else {
          // TRANSPOSED: [f][token_p6]; rbase 4-aligned => 4 contiguous tokens
          int tp = (rbase & ~63) | p6(rbase & 63);
          bf16x4 pack;
#pragma unroll
          for (int rr = 0; rr < 4; rr++)
            pack[rr] = (bf16_t)(seg == 1 ? phi_fn(v[rr]) : v[rr]);
          bf16_t* dst = (seg == 1) ? o1 : o2;
          *(bf16x4*)(dst + (size_t)f * 16384 + tp) = pack;
        }
      } else if constexpr (MODE == 1) {
        float bv = bias[col];
        int cs = permc(col);                 // FFN2's k-dim
#pragma unroll
        for (int rr = 0; rr < 4; rr++)
          o0[(size_t)(rbase + rr) * 1024 + cs] = (bf16_t)gelu_fn(v[rr] + bv);
      } else {
        float bv = bias[col];
#pragma unroll
        for (int rr = 0; rr < 4; rr++)
          o0[(size_t)(rbase + rr) * 1024 + col] = (bf16_t)(v[rr] + bv);
      }
    }
  }
}

// ---------------- kv_sum via MFMA (C[d][f] = sum_n phikT[d][n] * vT[f][n]) ---

__global__ __launch_bounds__(256, 4)
void kvsum_mfma_kernel(const bf16_t* __restrict__ phikT, const bf16_t* __restrict__ vT,
                       float* __restrict__ P)
{
  __shared__ bf16_t As[128 * 64];
  __shared__ bf16_t Bs[128 * 64];
  const int h = blockIdx.y, c = blockIdx.x;
  const bf16_t* A = phikT + (size_t)h * 128 * 16384;
  const bf16_t* B = vT    + (size_t)h * 128 * 16384;
  const int tid = threadIdx.x, lane = tid & 63, wave = tid >> 6;
  const int wr = (wave >> 1) * 64, wc = (wave & 1) * 64;
  const int l15 = lane & 15, g = lane >> 4;
  const int cb = wave * 256;
  f32x4 acc[4][4] = {};

  for (int kk = 0; kk < 4; ++kk) {
    const int kt = c * 256 + kk * 64;
    __syncthreads();
#pragma unroll
    for (int it = 0; it < 4; ++it) {
      int ch = cb + it * 64 + lane;
      int r = ch >> 3;
      int csrc = (ch & 7) ^ (r & 7);
      gload16(A + (size_t)r * 16384 + kt + csrc * 8, As + (size_t)(cb + it * 64) * 8);
      gload16(B + (size_t)r * 16384 + kt + csrc * 8, Bs + (size_t)(cb + it * 64) * 8);
    }
    __syncthreads();
#pragma unroll
    for (int ks = 0; ks < 2; ++ks) {
      bf16x8 af[4], bfr[4];
#pragma unroll
      for (int i = 0; i < 4; i++) af[i]  = ldsf128(As, wr + i * 16 + l15, 128, ks * 64 + 16 * g);
#pragma unroll
      for (int i = 0; i < 4; i++) bfr[i] = ldsf128(Bs, wc + i * 16 + l15, 128, ks * 64 + 16 * g);
#pragma unroll
      for (int i = 0; i < 4; i++)
#pragma unroll
        for (int j = 0; j < 4; j++)
          acc[i][j] = __builtin_amdgcn_mfma_f32_16x16x32_bf16(af[i], bfr[j], acc[i][j], 0, 0, 0);
    }
  }

  float* pb = P + ((size_t)h * 64 + c) * 16384;
#pragma unroll
  for (int i = 0; i < 4; i++) {
    int e = wr + i * 16 + g * 4;
#pragma unroll
    for (int j = 0; j < 4; j++) {
      int f = wc + j * 16 + l15;
      f32x4 v = acc[i][j];
#pragma unroll
      for (int rr = 0; rr < 4; rr++)
        pb[(size_t)(e + rr) * 128 + f] = v[rr];
    }
  }
}

// z[f] = sum_n phikT[f][n]  (coalesced row sum; perm-invariant)
__global__ void zsumT_kernel(const bf16_t* __restrict__ phikT, float* __restrict__ z) {
  __shared__ float red[4];
  int f = blockIdx.x, tid = threadIdx.x;
  const bf16_t* p = phikT + (size_t)f * 16384 + tid * 64;
  float s = 0.f;
#pragma unroll
  for (int j = 0; j < 8; j++) {
    bf16x8 v8 = *(const bf16x8*)(p + j * 8);
#pragma unroll
    for (int i = 0; i < 8; i++) s += (float)v8[i];
  }
#pragma unroll
  for (int o = 32; o > 0; o >>= 1) s += __shfl_down(s, o);
  if ((tid & 63) == 0) red[tid >> 6] = s;
  __syncthreads();
  if (tid == 0) z[f] = red[0] + red[1] + red[2] + red[3];
}

// Reduce 64 partials/head: Mbt[h][f][d_storage] = sum_c P[h][c][d][f].
__global__ void reduce_kvsum_kernel(const float* __restrict__ P, bf16_t* __restrict__ Mbt)
{
  int i = blockIdx.x * 256 + threadIdx.x;    // [0, 131072)
  int h = i >> 14, d = (i >> 7) & 127, f = i & 127;
  const float* p = P + (size_t)h * 64 * 16384 + (size_t)d * 128 + f;
  float s = 0.f;
#pragma unroll 8
  for (int c = 0; c < 64; ++c) s += p[(size_t)c * 16384];
  int ds = (d & 64) | p6(d & 63);
  Mbt[(size_t)h * 16384 + f * 128 + ds] = (bf16_t)s;
}

// ---------------- attention num/den/t ----------------

__global__ __launch_bounds__(256, 3)
void attn_t_kernel(const bf16_t* __restrict__ phiq, const bf16_t* __restrict__ Mbt,
                   const float* __restrict__ z, bf16_t* __restrict__ tout)
{
  __shared__ bf16_t As[64 * 128];   // phiq rows (storage order)
  __shared__ bf16_t Bs[128 * 128];  // Mbt[h] : [f][d_storage]
  __shared__ float  zs[128];        // z indexed by d_storage
  __shared__ float  dens[64];
  int h = blockIdx.y, row0 = blockIdx.x * 64;
  int tid = threadIdx.x, lane = tid & 63, wave = tid >> 6;
  int wr = (wave >> 1) * 32, wc = (wave & 1) * 64;
  int l15 = lane & 15, g = lane >> 4;

#pragma unroll
  for (int it = 0; it < 4; ++it) {          // A: 64x128 = 1024 chunks
    int ch = it * 256 + tid;
    int r = ch >> 4, c8 = ch & 15;
    int cs = c8 ^ (r & 7);
    *(bf16x8*)(As + r * 128 + cs * 8) = *(const bf16x8*)(phiq + (size_t)(row0 + r) * 1024 + h * 128 + c8 * 8);
  }
#pragma unroll
  for (int it = 0; it < 8; ++it) {          // B: 128x128 = 2048 chunks
    int ch = it * 256 + tid;
    int r = ch >> 4, c8 = ch & 15;
    int cs = c8 ^ (r & 7);
    *(bf16x8*)(Bs + r * 128 + cs * 8) = *(const bf16x8*)(Mbt + (size_t)h * 16384 + ch * 8);
  }
  if (tid < 128) zs[tid] = z[h * 128 + ((tid & 64) | p6i(tid & 63))];
  __syncthreads();

  f32x4 acc[2][4] = {};
#pragma unroll
  for (int ks = 0; ks < 4; ++ks) {
    bf16x8 af[2], bfr[4];
#pragma unroll
    for (int i = 0; i < 2; i++) af[i]  = ldsf128(As, wr + i * 16 + l15, 256, ks * 64 + 16 * g);
#pragma unroll
    for (int j = 0; j < 4; j++) bfr[j] = ldsf128(Bs, wc + j * 16 + l15, 256, ks * 64 + 16 * g);
#pragma unroll
    for (int i = 0; i < 2; i++)
#pragma unroll
      for (int j = 0; j < 4; j++)
        acc[i][j] = __builtin_amdgcn_mfma_f32_16x16x32_bf16(af[i], bfr[j], acc[i][j], 0, 0, 0);
  }

  if (tid < 64) {                            // den (storage-order dot, skewed, swizzle-aware)
    float s = 0.f;
    const char* p = (const char*)As + tid * 256;
    int sw = (tid & 7) << 4;
    for (int d0 = 0; d0 < 128; ++d0) {
      int d = (d0 + tid) & 127;
      bf16_t kv = *(const bf16_t*)(p + ((2 * d) ^ sw));
      s += (float)kv * zs[d];
    }
    dens[tid] = s;
  }
  __syncthreads();

#pragma unroll
  for (int i = 0; i < 2; i++) {
    int lr = wr + i * 16 + g * 4;
#pragma unroll
    for (int j = 0; j < 4; j++) {
      int col = h * 128 + wc + j * 16 + l15;  // logical head-major
      f32x4 v = acc[i][j];
#pragma unroll
      for (int rr = 0; rr < 4; rr++) {
        float den = dens[lr + rr] + 1e-6f;
        tout[(size_t)(row0 + lr + rr) * 1024 + col] = (bf16_t)(v[rr] / den);
      }
    }
  }
}

// ---------------- LayerNorms ----------------

// y = LN(unpermute(t) + x) * g + b   (y written PERM'd for FFN1's k-dim)
__global__ __launch_bounds__(256, 2)
void ln1_kernel(const bf16_t* __restrict__ t, const float* __restrict__ x,
                const float* __restrict__ gma, const float* __restrict__ bta,
                bf16_t* __restrict__ y)
{
  __shared__ float s[1024];
  __shared__ float rsum[4], rsq[4];
  int n = blockIdx.x, tid = threadIdx.x;
#pragma unroll
  for (int k = 0; k < 4; k++) {
    int p = k * 256 + tid;
    float tv = (float)t[(size_t)n * 1024 + p];
    int c = ((p & 127) << 3) | (p >> 7);     // head-major -> natural
    s[c] = tv;
  }
  __syncthreads();
  float sum = 0.f, sq = 0.f, sv[4];
#pragma unroll
  for (int k = 0; k < 4; k++) {
    int c = k * 256 + tid;
    float v = s[c] + x[(size_t)n * 1024 + c];
    sv[k] = v; sum += v; sq += v * v;
  }
#pragma unroll
  for (int o = 32; o > 0; o >>= 1) { sum += __shfl_down(sum, o); sq += __shfl_down(sq, o); }
  if ((tid & 63) == 0) { rsum[tid >> 6] = sum; rsq[tid >> 6] = sq; }
  __syncthreads();
  sum = rsum[0] + rsum[1] + rsum[2] + rsum[3];
  sq  = rsq[0] + rsq[1] + rsq[2] + rsq[3];
  float mu = sum * (1.f / 1024.f);
  float var = sq * (1.f / 1024.f) - mu * mu;
  float rs = rsqrtf(var + 1e-5f);
#pragma unroll
  for (int k = 0; k < 4; k++) {
    int c = k * 256 + tid;
    y[(size_t)n * 1024 + permc(c)] = (bf16_t)((sv[k] - mu) * rs * gma[c] + bta[c]);
  }
}

// out = LN(f + y) * g + b   (f natural; y stored PERM'd; out f32 natural)
__global__ __launch_bounds__(256, 2)
void ln2_kernel(const bf16_t* __restrict__ f, const bf16_t* __restrict__ y,
                const float* __restrict__ gma, const float* __restrict__ bta,
                float* __restrict__ out)
{
  __shared__ float rsum[4], rsq[4];
  int n = blockIdx.x, tid = threadIdx.x;
  float sum = 0.f, sq = 0.f, sv[4];
#pragma unroll
  for (int k = 0; k < 4; k++) {
    int c = k * 256 + tid;
    float v = (float)f[(size_t)n * 1024 + c] + (float)y[(size_t)n * 1024 + permc(c)];
    sv[k] = v; sum += v; sq += v * v;
  }
#pragma unroll
  for (int o = 32; o > 0; o >>= 1) { sum += __shfl_down(sum, o); sq += __shfl_down(sq, o); }
  if ((tid & 63) == 0) { rsum[tid >> 6] = sum; rsq[tid >> 6] = sq; }
  __syncthreads();
  sum = rsum[0] + rsum[1] + rsum[2] + rsum[3];
  sq  = rsq[0] + rsq[1] + rsq[2] + rsq[3];
  float mu = sum * (1.f / 1024.f);
  float var = sq * (1.f / 1024.f) - mu * mu;
  float rs = rsqrtf(var + 1e-5f);
#pragma unroll
  for (int k = 0; k < 4; k++) {
    int c = k * 256 + tid;
    out[(size_t)n * 1024 + c] = (sv[k] - mu) * rs * gma[c] + bta[c];
  }
}

// ---------------- launcher ----------------

extern "C" void kernel_launch(void* const* d_in, const int* in_sizes, int n_in,
                              void* d_out, int out_size, void* d_ws, size_t ws_size,
                              hipStream_t stream)
{
  const float* x    = (const float*)d_in[0];
  const float* Wq   = (const float*)d_in[1];
  const float* Wkv  = (const float*)d_in[2];
  const float* g1   = (const float*)d_in[3];
  const float* bt1  = (const float*)d_in[4];
  const float* W1   = (const float*)d_in[5];
  const float* b1   = (const float*)d_in[6];
  const float* W2   = (const float*)d_in[7];
  const float* b2   = (const float*)d_in[8];
  const float* g2   = (const float*)d_in[9];
  const float* bt2  = (const float*)d_in[10];
  float* out = (float*)d_out;

  char* ws = (char*)d_ws;
  size_t off = 0;
  auto alloc = [&](size_t bytes) { void* p = ws + off; off += (bytes + 255) & ~(size_t)255; return p; };

  const size_t NC2 = (size_t)NROWS * CDIM * 2;          // 33.5 MB (bf16)
  bf16_t* xb    = (bf16_t*)alloc(NC2);                  // xb; later: kvsum partials P; later: t
  bf16_t* wqkv  = (bf16_t*)alloc((size_t)3072 * 1024 * 2);
  bf16_t* w1bt  = (bf16_t*)alloc((size_t)1024 * 1024 * 2);
  bf16_t* w2bt  = (bf16_t*)alloc((size_t)1024 * 1024 * 2);
  bf16_t* phiq  = (bf16_t*)alloc(NC2);
  bf16_t* phikT = (bf16_t*)alloc(NC2);                  // [1024][16384]; later reused as h
  bf16_t* vT    = (bf16_t*)alloc(NC2);                  // [1024][16384]; later reused as f
  bf16_t* ybuf  = (bf16_t*)alloc(NC2);
  float*  zbuf  = (float*)alloc(4096);                  // z[1024]
  bf16_t* Mbt   = (bf16_t*)alloc(262144);
  float*  Pbuf  = (float*)xb;                           // alias: 8*64*16384 f32 = exactly NC2 bytes
  bf16_t* tbuf  = xb;                                   // alias (P dead after reduce)
  bf16_t* hbuf  = phikT;                                // alias (phikT dead after kvsum/zsum)
  bf16_t* fbuf  = vT;                                   // alias (vT dead after kvsum)

  cast_x_kernel<<<2048, 256, 0, stream>>>(x, xb, (long)NROWS * CDIM / 8);
  prep_w_kernel<<<dim3(16, 16, 5), 256, 0, stream>>>(Wq, Wkv, W1, W2, wqkv, w1bt, w2bt);

  gemm8p_kernel<0><<<64 * 12, 512, 0, stream>>>(xb, wqkv, nullptr, phiq, phikT, vT, 12);
  kvsum_mfma_kernel<<<dim3(64, 8), 256, 0, stream>>>(phikT, vT, Pbuf);
  zsumT_kernel<<<1024, 256, 0, stream>>>(phikT, zbuf);
  reduce_kvsum_kernel<<<512, 256, 0, stream>>>(Pbuf, Mbt);
  attn_t_kernel<<<dim3(256, 8), 256, 0, stream>>>(phiq, Mbt, zbuf, tbuf);
  ln1_kernel<<<NROWS, 256, 0, stream>>>(tbuf, x, g1, bt1, ybuf);

  gemm8p_kernel<1><<<64 * 4, 512, 0, stream>>>(ybuf, w1bt, b1, hbuf, nullptr, nullptr, 4);
  gemm8p_kernel<2><<<64 * 4, 512, 0, stream>>>(hbuf, w2bt, b2, fbuf, nullptr, nullptr, 4);
  ln2_kernel<<<NROWS, 256, 0, stream>>>(fbuf, ybuf, g2, bt2, out);
}

// Round 12
// 340.813 us; speedup vs baseline: 1.0903x; 1.0903x over previous
//
#include <hip/hip_runtime.h>
#include <hip/hip_bf16.h>
#include <cstdint>
#include <cstddef>

typedef __bf16 bf16_t;
typedef bf16_t bf16x4 __attribute__((ext_vector_type(4)));
typedef bf16_t bf16x8 __attribute__((ext_vector_type(8)));
typedef float f32x4 __attribute__((ext_vector_type(4)));

static constexpr int NROWS = 16384;
static constexpr int CDIM  = 1024;

// ---------------- K-permutation (contiguous MFMA fragments) ----------------
// p6: k=[b5 b4 b3 b2 b1 b0] -> s=[b5 b3 b2 b4 b1 b0]; maps {0..31}->{0..31};
// preserves k&3, so 4-aligned groups stay 4-contiguous.
__device__ __forceinline__ int p6(int k) {
  return (k & 32) | ((k & 12) << 1) | ((k & 16) >> 2) | (k & 3);
}
__device__ __forceinline__ int p6i(int s) {
  return (s & 32) | ((s & 4) << 2) | ((s & 24) >> 1) | (s & 3);
}
__device__ __forceinline__ int permc(int c) {        // within-64 perm of a wider index
  return (c & ~63) | p6(c & 63);
}

// ---------------- helpers ----------------

__device__ __forceinline__ void gload16(const bf16_t* g, bf16_t* l) {
  __builtin_amdgcn_global_load_lds((const __attribute__((address_space(1))) void*)g,
                                   (__attribute__((address_space(3))) void*)l, 16, 0, 0);
}

// Single-b128 fragment load from a row-major LDS tile whose 16B granules are
// XOR-swizzled: granule byte-addr ^= (row&7)<<4. kbyte is a multiple of 16.
__device__ __forceinline__ bf16x8 ldsf128(const bf16_t* lds, int row, int ldbytes, int kbyte) {
  const char* p = (const char*)lds + row * ldbytes + (kbyte ^ ((row & 7) << 4));
  return *(const bf16x8*)p;
}

__device__ __forceinline__ float phi_fn(float v) {           // elu + 1
  return v > 0.f ? v + 1.f : expf(v);
}
__device__ __forceinline__ float gelu_fn(float v) {          // exact gelu
  return 0.5f * v * (1.f + erff(v * 0.70710678118654752f));
}

// ---------------- elementwise / prep ----------------

// xb[row][PERM(c)] = (bf16) x[row][c]  -- written chunk-wise (8 elems/chunk).
__global__ void cast_x_kernel(const float* __restrict__ x, bf16_t* __restrict__ xb, long nchunks) {
  long i = (long)blockIdx.x * blockDim.x + threadIdx.x;
  long stride = (long)gridDim.x * blockDim.x;
  for (long c = i; c < nchunks; c += stride) {
    long row = c >> 7;
    int p0 = (int)(c & 127) << 3;            // storage position of this 8-elem chunk
    int group = p0 & ~63;
    int ccl = (p0 >> 3) & 7;                 // chunk within 64-group
    int klo = ((ccl & 4) << 3) | ((ccl & 3) << 2);   // logical k of elems 0-3 (4-7 = +16)
    const float* src = x + row * 1024 + group + klo;
    float4 a = *(const float4*)src;
    float4 b = *(const float4*)(src + 16);
    bf16x8 o;
    o[0] = (bf16_t)a.x; o[1] = (bf16_t)a.y; o[2] = (bf16_t)a.z; o[3] = (bf16_t)a.w;
    o[4] = (bf16_t)b.x; o[5] = (bf16_t)b.y; o[6] = (bf16_t)b.z; o[7] = (bf16_t)b.w;
    *(bf16x8*)(xb + row * 1024 + p0) = o;
  }
}

// Transpose-cast weights to column-major bf16 (Bt[n][k_perm]); modes 0-2 also
// apply the head-major column permutation perm(c) = (c%8)*128 + c/8.
__global__ void prep_w_kernel(const float* __restrict__ Wq, const float* __restrict__ Wkv,
                              const float* __restrict__ W1, const float* __restrict__ W2,
                              bf16_t* __restrict__ wqkv_bt, bf16_t* __restrict__ w1bt,
                              bf16_t* __restrict__ w2bt) {
  __shared__ float tile[64][65];
  int mode = blockIdx.z;
  const float* src; int ld; bf16_t* dst; int permute;
  if (mode == 0)      { src = Wq;          ld = 1024; dst = wqkv_bt;                       permute = 1; }
  else if (mode == 1) { src = Wkv;         ld = 2048; dst = wqkv_bt + (size_t)1024 * 1024; permute = 1; }
  else if (mode == 2) { src = Wkv + 1024;  ld = 2048; dst = wqkv_bt + (size_t)2048 * 1024; permute = 1; }
  else if (mode == 3) { src = W1;          ld = 1024; dst = w1bt;                          permute = 0; }
  else                { src = W2;          ld = 1024; dst = w2bt;                          permute = 0; }
  int r0 = blockIdx.x * 64, c0 = blockIdx.y * 64;
  int tid = threadIdx.x;
#pragma unroll
  for (int i = 0; i < 16; i++) {
    int idx = i * 256 + tid; int rr = idx >> 6, cc = idx & 63;
    tile[rr][cc] = src[(size_t)(r0 + rr) * ld + c0 + cc];
  }
  __syncthreads();
#pragma unroll
  for (int i = 0; i < 16; i++) {
    int idx = i * 256 + tid; int cc = idx >> 6, rr = idx & 63;
    int c = c0 + cc;
    int a = permute ? (((c & 7) << 7) | (c >> 3)) : c;
    dst[(size_t)a * 1024 + r0 + p6(rr)] = (bf16_t)tile[rr][cc];
  }
}

// ---------------- main GEMM (128x128, gload_lds, b128 frags, XCD swizzle) ---
// out = A[M][Kp] @ Bt[N][Kp]^T. LDS dest linear, source granule pre-XOR'd,
// fragment reads via swizzled ldsf128 (single ds_read_b128, conflict-free).
// 1D grid (M/128)*(N/128), %8==0; XCD-bijective swizzle gives each XCD a
// contiguous row-major work chunk (16 A-row-panels = 4MB ~ its L2 for QKV).
// MODE 0: QKV (N=3072): seg0 phi->phiq[n][permc(f)];
//         seg1 phi->phikT[f][token_p6]; seg2 v->vT[f][token_p6]  (TRANSPOSED)
// MODE 1: FFN1: gelu(acc+bias) -> o0 at PERM'd col
// MODE 2: FFN2: acc+bias -> o0 natural

template<int MODE>
__global__ __launch_bounds__(256, 4)
void gemm_bt_kernel(const bf16_t* __restrict__ A, const bf16_t* __restrict__ Bt,
                    const float* __restrict__ bias,
                    bf16_t* __restrict__ o0, bf16_t* __restrict__ o1, bf16_t* __restrict__ o2,
                    int tn_count, int K)
{
  __shared__ bf16_t As[128 * 64];
  __shared__ bf16_t Bs[128 * 64];
  const int tid  = threadIdx.x;
  const int lane = tid & 63;
  const int wave = tid >> 6;
  const int wr = (wave >> 1) * 64, wc = (wave & 1) * 64;
  const int l15 = lane & 15, g = lane >> 4;
  const int cpx = gridDim.x >> 3;            // XCD-bijective swizzle (grid%8==0)
  const int swz = ((int)blockIdx.x & 7) * cpx + ((int)blockIdx.x >> 3);
  const int row0 = (swz / tn_count) * 128, col0 = (swz % tn_count) * 128;
  const int cb = wave * 256;                 // this wave's 256-chunk slice of 1024
  f32x4 acc[4][4] = {};

  for (int kt = 0; kt < K; kt += 64) {
    __syncthreads();                         // prior iter's LDS reads done
#pragma unroll
    for (int it = 0; it < 4; ++it) {
      int ch = cb + it * 64 + lane;          // LDS 16B-chunk id (linear dest)
      int r = ch >> 3;
      int csrc = (ch & 7) ^ (r & 7);         // inverse-swizzled source granule
      gload16(A  + (size_t)(row0 + r) * K + kt + csrc * 8, As + (size_t)(cb + it * 64) * 8);
      gload16(Bt + (size_t)(col0 + r) * K + kt + csrc * 8, Bs + (size_t)(cb + it * 64) * 8);
    }
    __syncthreads();
#pragma unroll
    for (int ks = 0; ks < 2; ++ks) {
      bf16x8 af[4], bfr[4];
#pragma unroll
      for (int i = 0; i < 4; i++) af[i]  = ldsf128(As, wr + i * 16 + l15, 128, ks * 64 + 16 * g);
#pragma unroll
      for (int i = 0; i < 4; i++) bfr[i] = ldsf128(Bs, wc + i * 16 + l15, 128, ks * 64 + 16 * g);
#pragma unroll
      for (int i = 0; i < 4; i++)
#pragma unroll
        for (int j = 0; j < 4; j++)
          acc[i][j] = __builtin_amdgcn_mfma_f32_16x16x32_bf16(af[i], bfr[j], acc[i][j], 0, 0, 0);
    }
  }

  // epilogue: D col = l&15, row = 4*(lane>>4) + reg
#pragma unroll
  for (int i = 0; i < 4; i++) {
    int rbase = row0 + wr + i * 16 + g * 4;
#pragma unroll
    for (int j = 0; j < 4; j++) {
      int col = col0 + wc + j * 16 + l15;
      f32x4 v = acc[i][j];
      if constexpr (MODE == 0) {
        int seg = col >> 10;
        int f   = col & 1023;                // head-major feature
        if (seg == 0) {
          int cl = permc(f);                 // phiq: [n][f_perm] (attn's k-dim)
#pragma unroll
          for (int rr = 0; rr < 4; rr++)
            o0[(size_t)(rbase + rr) * 1024 + cl] = (bf16_t)phi_fn(v[rr]);
        } else {
          // TRANSPOSED: [f][token_p6]; rbase 4-aligned => 4 contiguous tokens
          int tp = (rbase & ~63) | p6(rbase & 63);
          bf16x4 pack;
#pragma unroll
          for (int rr = 0; rr < 4; rr++)
            pack[rr] = (bf16_t)(seg == 1 ? phi_fn(v[rr]) : v[rr]);
          bf16_t* dst = (seg == 1) ? o1 : o2;
          *(bf16x4*)(dst + (size_t)f * 16384 + tp) = pack;
        }
      } else if constexpr (MODE == 1) {
        float bv = bias[col];
        int cs = permc(col);                 // FFN2's k-dim
#pragma unroll
        for (int rr = 0; rr < 4; rr++)
          o0[(size_t)(rbase + rr) * 1024 + cs] = (bf16_t)gelu_fn(v[rr] + bv);
      } else {
        float bv = bias[col];
#pragma unroll
        for (int rr = 0; rr < 4; rr++)
          o0[(size_t)(rbase + rr) * 1024 + col] = (bf16_t)(v[rr] + bv);
      }
    }
  }
}

// ---------------- kv_sum via MFMA (C[d][f] = sum_n phikT[d][n] * vT[f][n]) ---
// 1D grid 512: h = bid&7 clusters all 64 blocks of one head onto one XCD
// (dispatch round-robin) for phikT/vT panel L2 locality.

__global__ __launch_bounds__(256, 4)
void kvsum_mfma_kernel(const bf16_t* __restrict__ phikT, const bf16_t* __restrict__ vT,
                       float* __restrict__ P)
{
  __shared__ bf16_t As[128 * 64];
  __shared__ bf16_t Bs[128 * 64];
  const int h = (int)blockIdx.x & 7, c = (int)blockIdx.x >> 3;
  const bf16_t* A = phikT + (size_t)h * 128 * 16384;
  const bf16_t* B = vT    + (size_t)h * 128 * 16384;
  const int tid = threadIdx.x, lane = tid & 63, wave = tid >> 6;
  const int wr = (wave >> 1) * 64, wc = (wave & 1) * 64;
  const int l15 = lane & 15, g = lane >> 4;
  const int cb = wave * 256;
  f32x4 acc[4][4] = {};

  for (int kk = 0; kk < 4; ++kk) {
    const int kt = c * 256 + kk * 64;
    __syncthreads();
#pragma unroll
    for (int it = 0; it < 4; ++it) {
      int ch = cb + it * 64 + lane;
      int r = ch >> 3;
      int csrc = (ch & 7) ^ (r & 7);
      gload16(A + (size_t)r * 16384 + kt + csrc * 8, As + (size_t)(cb + it * 64) * 8);
      gload16(B + (size_t)r * 16384 + kt + csrc * 8, Bs + (size_t)(cb + it * 64) * 8);
    }
    __syncthreads();
#pragma unroll
    for (int ks = 0; ks < 2; ++ks) {
      bf16x8 af[4], bfr[4];
#pragma unroll
      for (int i = 0; i < 4; i++) af[i]  = ldsf128(As, wr + i * 16 + l15, 128, ks * 64 + 16 * g);
#pragma unroll
      for (int i = 0; i < 4; i++) bfr[i] = ldsf128(Bs, wc + i * 16 + l15, 128, ks * 64 + 16 * g);
#pragma unroll
      for (int i = 0; i < 4; i++)
#pragma unroll
        for (int j = 0; j < 4; j++)
          acc[i][j] = __builtin_amdgcn_mfma_f32_16x16x32_bf16(af[i], bfr[j], acc[i][j], 0, 0, 0);
    }
  }

  float* pb = P + ((size_t)h * 64 + c) * 16384;
#pragma unroll
  for (int i = 0; i < 4; i++) {
    int e = wr + i * 16 + g * 4;
#pragma unroll
    for (int j = 0; j < 4; j++) {
      int f = wc + j * 16 + l15;
      f32x4 v = acc[i][j];
#pragma unroll
      for (int rr = 0; rr < 4; rr++)
        pb[(size_t)(e + rr) * 128 + f] = v[rr];
    }
  }
}

// z[f] = sum_n phikT[f][n]  (coalesced row sum; perm-invariant)
__global__ void zsumT_kernel(const bf16_t* __restrict__ phikT, float* __restrict__ z) {
  __shared__ float red[4];
  int f = blockIdx.x, tid = threadIdx.x;
  const bf16_t* p = phikT + (size_t)f * 16384 + tid * 64;
  float s = 0.f;
#pragma unroll
  for (int j = 0; j < 8; j++) {
    bf16x8 v8 = *(const bf16x8*)(p + j * 8);
#pragma unroll
    for (int i = 0; i < 8; i++) s += (float)v8[i];
  }
#pragma unroll
  for (int o = 32; o > 0; o >>= 1) s += __shfl_down(s, o);
  if ((tid & 63) == 0) red[tid >> 6] = s;
  __syncthreads();
  if (tid == 0) z[f] = red[0] + red[1] + red[2] + red[3];
}

// Reduce 64 partials/head: Mbt[h][f][d_storage] = sum_c P[h][c][d][f].
// d gets p6-permuted to match phiq's k-dim storage layout.
__global__ void reduce_kvsum_kernel(const float* __restrict__ P, bf16_t* __restrict__ Mbt)
{
  int i = blockIdx.x * 256 + threadIdx.x;    // [0, 131072)
  int h = i >> 14, d = (i >> 7) & 127, f = i & 127;
  const float* p = P + (size_t)h * 64 * 16384 + (size_t)d * 128 + f;
  float s = 0.f;
#pragma unroll 8
  for (int c = 0; c < 64; ++c) s += p[(size_t)c * 16384];
  int ds = (d & 64) | p6(d & 63);
  Mbt[(size_t)h * 16384 + f * 128 + ds] = (bf16_t)s;
}

// ---------------- attention num/den/t ----------------

__global__ __launch_bounds__(256, 3)
void attn_t_kernel(const bf16_t* __restrict__ phiq, const bf16_t* __restrict__ Mbt,
                   const float* __restrict__ z, bf16_t* __restrict__ tout)
{
  __shared__ bf16_t As[64 * 128];   // phiq rows (storage order)
  __shared__ bf16_t Bs[128 * 128];  // Mbt[h] : [f][d_storage]
  __shared__ float  zs[128];        // z indexed by d_storage
  __shared__ float  dens[64];
  int h = blockIdx.y, row0 = blockIdx.x * 64;
  int tid = threadIdx.x, lane = tid & 63, wave = tid >> 6;
  int wr = (wave >> 1) * 32, wc = (wave & 1) * 64;
  int l15 = lane & 15, g = lane >> 4;

#pragma unroll
  for (int it = 0; it < 4; ++it) {          // A: 64x128 = 1024 chunks
    int ch = it * 256 + tid;
    int r = ch >> 4, c8 = ch & 15;
    int cs = c8 ^ (r & 7);
    *(bf16x8*)(As + r * 128 + cs * 8) = *(const bf16x8*)(phiq + (size_t)(row0 + r) * 1024 + h * 128 + c8 * 8);
  }
#pragma unroll
  for (int it = 0; it < 8; ++it) {          // B: 128x128 = 2048 chunks
    int ch = it * 256 + tid;
    int r = ch >> 4, c8 = ch & 15;
    int cs = c8 ^ (r & 7);
    *(bf16x8*)(Bs + r * 128 + cs * 8) = *(const bf16x8*)(Mbt + (size_t)h * 16384 + ch * 8);
  }
  if (tid < 128) zs[tid] = z[h * 128 + ((tid & 64) | p6i(tid & 63))];
  __syncthreads();

  f32x4 acc[2][4] = {};
#pragma unroll
  for (int ks = 0; ks < 4; ++ks) {
    bf16x8 af[2], bfr[4];
#pragma unroll
    for (int i = 0; i < 2; i++) af[i]  = ldsf128(As, wr + i * 16 + l15, 256, ks * 64 + 16 * g);
#pragma unroll
    for (int j = 0; j < 4; j++) bfr[j] = ldsf128(Bs, wc + j * 16 + l15, 256, ks * 64 + 16 * g);
#pragma unroll
    for (int i = 0; i < 2; i++)
#pragma unroll
      for (int j = 0; j < 4; j++)
        acc[i][j] = __builtin_amdgcn_mfma_f32_16x16x32_bf16(af[i], bfr[j], acc[i][j], 0, 0, 0);
  }

  if (tid < 64) {                            // den (storage-order dot, skewed, swizzle-aware)
    float s = 0.f;
    const char* p = (const char*)As + tid * 256;
    int sw = (tid & 7) << 4;
    for (int d0 = 0; d0 < 128; ++d0) {
      int d = (d0 + tid) & 127;
      bf16_t kv = *(const bf16_t*)(p + ((2 * d) ^ sw));
      s += (float)kv * zs[d];
    }
    dens[tid] = s;
  }
  __syncthreads();

#pragma unroll
  for (int i = 0; i < 2; i++) {
    int lr = wr + i * 16 + g * 4;
#pragma unroll
    for (int j = 0; j < 4; j++) {
      int col = h * 128 + wc + j * 16 + l15;  // logical head-major
      f32x4 v = acc[i][j];
#pragma unroll
      for (int rr = 0; rr < 4; rr++) {
        float den = dens[lr + rr] + 1e-6f;
        tout[(size_t)(row0 + lr + rr) * 1024 + col] = (bf16_t)(v[rr] / den);
      }
    }
  }
}

// ---------------- LayerNorms ----------------

// y = LN(unpermute(t) + x) * g + b   (y written PERM'd for FFN1's k-dim)
__global__ __launch_bounds__(256, 2)
void ln1_kernel(const bf16_t* __restrict__ t, const float* __restrict__ x,
                const float* __restrict__ gma, const float* __restrict__ bta,
                bf16_t* __restrict__ y)
{
  __shared__ float s[1024];
  __shared__ float rsum[4], rsq[4];
  int n = blockIdx.x, tid = threadIdx.x;
#pragma unroll
  for (int k = 0; k < 4; k++) {
    int p = k * 256 + tid;
    float tv = (float)t[(size_t)n * 1024 + p];
    int c = ((p & 127) << 3) | (p >> 7);     // head-major -> natural
    s[c] = tv;
  }
  __syncthreads();
  float sum = 0.f, sq = 0.f, sv[4];
#pragma unroll
  for (int k = 0; k < 4; k++) {
    int c = k * 256 + tid;
    float v = s[c] + x[(size_t)n * 1024 + c];
    sv[k] = v; sum += v; sq += v * v;
  }
#pragma unroll
  for (int o = 32; o > 0; o >>= 1) { sum += __shfl_down(sum, o); sq += __shfl_down(sq, o); }
  if ((tid & 63) == 0) { rsum[tid >> 6] = sum; rsq[tid >> 6] = sq; }
  __syncthreads();
  sum = rsum[0] + rsum[1] + rsum[2] + rsum[3];
  sq  = rsq[0] + rsq[1] + rsq[2] + rsq[3];
  float mu = sum * (1.f / 1024.f);
  float var = sq * (1.f / 1024.f) - mu * mu;
  float rs = rsqrtf(var + 1e-5f);
#pragma unroll
  for (int k = 0; k < 4; k++) {
    int c = k * 256 + tid;
    y[(size_t)n * 1024 + permc(c)] = (bf16_t)((sv[k] - mu) * rs * gma[c] + bta[c]);
  }
}

// out = LN(f + y) * g + b   (f natural; y stored PERM'd; out f32 natural)
__global__ __launch_bounds__(256, 2)
void ln2_kernel(const bf16_t* __restrict__ f, const bf16_t* __restrict__ y,
                const float* __restrict__ gma, const float* __restrict__ bta,
                float* __restrict__ out)
{
  __shared__ float rsum[4], rsq[4];
  int n = blockIdx.x, tid = threadIdx.x;
  float sum = 0.f, sq = 0.f, sv[4];
#pragma unroll
  for (int k = 0; k < 4; k++) {
    int c = k * 256 + tid;
    float v = (float)f[(size_t)n * 1024 + c] + (float)y[(size_t)n * 1024 + permc(c)];
    sv[k] = v; sum += v; sq += v * v;
  }
#pragma unroll
  for (int o = 32; o > 0; o >>= 1) { sum += __shfl_down(sum, o); sq += __shfl_down(sq, o); }
  if ((tid & 63) == 0) { rsum[tid >> 6] = sum; rsq[tid >> 6] = sq; }
  __syncthreads();
  sum = rsum[0] + rsum[1] + rsum[2] + rsum[3];
  sq  = rsq[0] + rsq[1] + rsq[2] + rsq[3];
  float mu = sum * (1.f / 1024.f);
  float var = sq * (1.f / 1024.f) - mu * mu;
  float rs = rsqrtf(var + 1e-5f);
#pragma unroll
  for (int k = 0; k < 4; k++) {
    int c = k * 256 + tid;
    out[(size_t)n * 1024 + c] = (sv[k] - mu) * rs * gma[c] + bta[c];
  }
}

// ---------------- launcher ----------------

extern "C" void kernel_launch(void* const* d_in, const int* in_sizes, int n_in,
                              void* d_out, int out_size, void* d_ws, size_t ws_size,
                              hipStream_t stream)
{
  const float* x    = (const float*)d_in[0];
  const float* Wq   = (const float*)d_in[1];
  const float* Wkv  = (const float*)d_in[2];
  const float* g1   = (const float*)d_in[3];
  const float* bt1  = (const float*)d_in[4];
  const float* W1   = (const float*)d_in[5];
  const float* b1   = (const float*)d_in[6];
  const float* W2   = (const float*)d_in[7];
  const float* b2   = (const float*)d_in[8];
  const float* g2   = (const float*)d_in[9];
  const float* bt2  = (const float*)d_in[10];
  float* out = (float*)d_out;

  char* ws = (char*)d_ws;
  size_t off = 0;
  auto alloc = [&](size_t bytes) { void* p = ws + off; off += (bytes + 255) & ~(size_t)255; return p; };

  const size_t NC2 = (size_t)NROWS * CDIM * 2;          // 33.5 MB (bf16)
  bf16_t* xb    = (bf16_t*)alloc(NC2);                  // xb; later: kvsum partials P; later: t
  bf16_t* wqkv  = (bf16_t*)alloc((size_t)3072 * 1024 * 2);
  bf16_t* w1bt  = (bf16_t*)alloc((size_t)1024 * 1024 * 2);
  bf16_t* w2bt  = (bf16_t*)alloc((size_t)1024 * 1024 * 2);
  bf16_t* phiq  = (bf16_t*)alloc(NC2);
  bf16_t* phikT = (bf16_t*)alloc(NC2);                  // [1024][16384]; later reused as h
  bf16_t* vT    = (bf16_t*)alloc(NC2);                  // [1024][16384]; later reused as f
  bf16_t* ybuf  = (bf16_t*)alloc(NC2);
  float*  zbuf  = (float*)alloc(4096);                  // z[1024]
  bf16_t* Mbt   = (bf16_t*)alloc(262144);
  float*  Pbuf  = (float*)xb;                           // alias: 8*64*16384 f32 = exactly NC2 bytes
  bf16_t* tbuf  = xb;                                   // alias (P dead after reduce)
  bf16_t* hbuf  = phikT;                                // alias (phikT dead after kvsum/zsum)
  bf16_t* fbuf  = vT;                                   // alias (vT dead after kvsum)

  cast_x_kernel<<<2048, 256, 0, stream>>>(x, xb, (long)NROWS * CDIM / 8);
  prep_w_kernel<<<dim3(16, 16, 5), 256, 0, stream>>>(Wq, Wkv, W1, W2, wqkv, w1bt, w2bt);

  gemm_bt_kernel<0><<<128 * 24, 256, 0, stream>>>(xb, wqkv, nullptr, phiq, phikT, vT, 24, 1024);
  kvsum_mfma_kernel<<<512, 256, 0, stream>>>(phikT, vT, Pbuf);
  zsumT_kernel<<<1024, 256, 0, stream>>>(phikT, zbuf);
  reduce_kvsum_kernel<<<512, 256, 0, stream>>>(Pbuf, Mbt);
  attn_t_kernel<<<dim3(256, 8), 256, 0, stream>>>(phiq, Mbt, zbuf, tbuf);
  ln1_kernel<<<NROWS, 256, 0, stream>>>(tbuf, x, g1, bt1, ybuf);

  gemm_bt_kernel<1><<<128 * 8, 256, 0, stream>>>(ybuf, w1bt, b1, hbuf, nullptr, nullptr, 8, 1024);
  gemm_bt_kernel<2><<<128 * 8, 256, 0, stream>>>(hbuf, w2bt, b2, fbuf, nullptr, nullptr, 8, 1024);
  ln2_kernel<<<NROWS, 256, 0, stream>>>(fbuf, ybuf, g2, bt2, out);
}

// Round 13
// 313.492 us; speedup vs baseline: 1.1854x; 1.0871x over previous
//
#include <hip/hip_runtime.h>
#include <hip/hip_bf16.h>
#include <cstdint>
#include <cstddef>

typedef __bf16 bf16_t;
typedef bf16_t bf16x4 __attribute__((ext_vector_type(4)));
typedef bf16_t bf16x8 __attribute__((ext_vector_type(8)));
typedef float f32x4 __attribute__((ext_vector_type(4)));

static constexpr int NROWS = 16384;
static constexpr int CDIM  = 1024;

// ---------------- K-permutation (contiguous MFMA fragments) ----------------
// p6: k=[b5 b4 b3 b2 b1 b0] -> s=[b5 b3 b2 b4 b1 b0]; maps {0..31}->{0..31};
// preserves k&3, so 4-aligned groups stay 4-contiguous.
__device__ __forceinline__ int p6(int k) {
  return (k & 32) | ((k & 12) << 1) | ((k & 16) >> 2) | (k & 3);
}
__device__ __forceinline__ int p6i(int s) {
  return (s & 32) | ((s & 4) << 2) | ((s & 24) >> 1) | (s & 3);
}
__device__ __forceinline__ int permc(int c) {        // within-64 perm of a wider index
  return (c & ~63) | p6(c & 63);
}

// ---------------- helpers ----------------

__device__ __forceinline__ void gload16(const bf16_t* g, bf16_t* l) {
  __builtin_amdgcn_global_load_lds((const __attribute__((address_space(1))) void*)g,
                                   (__attribute__((address_space(3))) void*)l, 16, 0, 0);
}

// Single-b128 fragment load from a row-major LDS tile whose 16B granules are
// XOR-swizzled: granule byte-addr ^= (row&7)<<4. kbyte is a multiple of 16.
__device__ __forceinline__ bf16x8 ldsf128(const bf16_t* lds, int row, int ldbytes, int kbyte) {
  const char* p = (const char*)lds + row * ldbytes + (kbyte ^ ((row & 7) << 4));
  return *(const bf16x8*)p;
}

__device__ __forceinline__ float phi_fn(float v) {           // elu + 1
  return v > 0.f ? v + 1.f : expf(v);
}
__device__ __forceinline__ float gelu_fn(float v) {          // exact gelu
  return 0.5f * v * (1.f + erff(v * 0.70710678118654752f));
}

// ---------------- elementwise / prep ----------------

// xb[row][PERM(c)] = (bf16) x[row][c]  -- written chunk-wise (8 elems/chunk).
__global__ void cast_x_kernel(const float* __restrict__ x, bf16_t* __restrict__ xb, long nchunks) {
  long i = (long)blockIdx.x * blockDim.x + threadIdx.x;
  long stride = (long)gridDim.x * blockDim.x;
  for (long c = i; c < nchunks; c += stride) {
    long row = c >> 7;
    int p0 = (int)(c & 127) << 3;            // storage position of this 8-elem chunk
    int group = p0 & ~63;
    int ccl = (p0 >> 3) & 7;                 // chunk within 64-group
    int klo = ((ccl & 4) << 3) | ((ccl & 3) << 2);   // logical k of elems 0-3 (4-7 = +16)
    const float* src = x + row * 1024 + group + klo;
    float4 a = *(const float4*)src;
    float4 b = *(const float4*)(src + 16);
    bf16x8 o;
    o[0] = (bf16_t)a.x; o[1] = (bf16_t)a.y; o[2] = (bf16_t)a.z; o[3] = (bf16_t)a.w;
    o[4] = (bf16_t)b.x; o[5] = (bf16_t)b.y; o[6] = (bf16_t)b.z; o[7] = (bf16_t)b.w;
    *(bf16x8*)(xb + row * 1024 + p0) = o;
  }
}

// Transpose-cast weights to column-major bf16 (Bt[n][k_perm]); modes 0-2 also
// apply the head-major column permutation perm(c) = (c%8)*128 + c/8.
__global__ void prep_w_kernel(const float* __restrict__ Wq, const float* __restrict__ Wkv,
                              const float* __restrict__ W1, const float* __restrict__ W2,
                              bf16_t* __restrict__ wqkv_bt, bf16_t* __restrict__ w1bt,
                              bf16_t* __restrict__ w2bt) {
  __shared__ float tile[64][65];
  int mode = blockIdx.z;
  const float* src; int ld; bf16_t* dst; int permute;
  if (mode == 0)      { src = Wq;          ld = 1024; dst = wqkv_bt;                       permute = 1; }
  else if (mode == 1) { src = Wkv;         ld = 2048; dst = wqkv_bt + (size_t)1024 * 1024; permute = 1; }
  else if (mode == 2) { src = Wkv + 1024;  ld = 2048; dst = wqkv_bt + (size_t)2048 * 1024; permute = 1; }
  else if (mode == 3) { src = W1;          ld = 1024; dst = w1bt;                          permute = 0; }
  else                { src = W2;          ld = 1024; dst = w2bt;                          permute = 0; }
  int r0 = blockIdx.x * 64, c0 = blockIdx.y * 64;
  int tid = threadIdx.x;
#pragma unroll
  for (int i = 0; i < 16; i++) {
    int idx = i * 256 + tid; int rr = idx >> 6, cc = idx & 63;
    tile[rr][cc] = src[(size_t)(r0 + rr) * ld + c0 + cc];
  }
  __syncthreads();
#pragma unroll
  for (int i = 0; i < 16; i++) {
    int idx = i * 256 + tid; int cc = idx >> 6, rr = idx & 63;
    int c = c0 + cc;
    int a = permute ? (((c & 7) << 7) | (c >> 3)) : c;
    dst[(size_t)a * 1024 + r0 + p6(rr)] = (bf16_t)tile[rr][cc];
  }
}

// ---------------- main GEMM (128x128, gload_lds, b128 frags) ----------------
// out = A[M][Kp] @ Bt[N][Kp]^T. LDS dest linear, source granule pre-XOR'd,
// fragment reads via swizzled ldsf128 (single ds_read_b128, conflict-free).
// 2D grid (M/128, N/128): blockIdx.x (row panel) is the fast dispatch dim, so
// row panel i lands on XCD i%8 for every col panel -> A panels stay L2-resident
// per-XCD across col panels (natural dispatch is already XCD-optimal; R12's
// explicit swizzle regressed FETCH 150->227 MB).
// MODE 0: QKV (N=3072): seg0 phi->phiq[n][permc(f)];
//         seg1 phi->phikT[f][token_p6]; seg2 v->vT[f][token_p6]  (TRANSPOSED)
// MODE 1: FFN1: gelu(acc+bias) -> o0 at PERM'd col
// MODE 2: FFN2: acc+bias -> o0 natural

template<int MODE>
__global__ __launch_bounds__(256, 4)
void gemm_bt_kernel(const bf16_t* __restrict__ A, const bf16_t* __restrict__ Bt,
                    const float* __restrict__ bias,
                    bf16_t* __restrict__ o0, bf16_t* __restrict__ o1, bf16_t* __restrict__ o2,
                    int M, int N, int K)
{
  __shared__ bf16_t As[128 * 64];
  __shared__ bf16_t Bs[128 * 64];
  const int tid  = threadIdx.x;
  const int lane = tid & 63;
  const int wave = tid >> 6;
  const int wr = (wave >> 1) * 64, wc = (wave & 1) * 64;
  const int l15 = lane & 15, g = lane >> 4;
  const int row0 = blockIdx.x * 128, col0 = blockIdx.y * 128;
  const int cb = wave * 256;                 // this wave's 256-chunk slice of 1024
  f32x4 acc[4][4] = {};

  for (int kt = 0; kt < K; kt += 64) {
    __syncthreads();                         // prior iter's LDS reads done
#pragma unroll
    for (int it = 0; it < 4; ++it) {
      int ch = cb + it * 64 + lane;          // LDS 16B-chunk id (linear dest)
      int r = ch >> 3;
      int csrc = (ch & 7) ^ (r & 7);         // inverse-swizzled source granule
      gload16(A  + (size_t)(row0 + r) * K + kt + csrc * 8, As + (size_t)(cb + it * 64) * 8);
      gload16(Bt + (size_t)(col0 + r) * K + kt + csrc * 8, Bs + (size_t)(cb + it * 64) * 8);
    }
    __syncthreads();
#pragma unroll
    for (int ks = 0; ks < 2; ++ks) {
      bf16x8 af[4], bfr[4];
#pragma unroll
      for (int i = 0; i < 4; i++) af[i]  = ldsf128(As, wr + i * 16 + l15, 128, ks * 64 + 16 * g);
#pragma unroll
      for (int i = 0; i < 4; i++) bfr[i] = ldsf128(Bs, wc + i * 16 + l15, 128, ks * 64 + 16 * g);
#pragma unroll
      for (int i = 0; i < 4; i++)
#pragma unroll
        for (int j = 0; j < 4; j++)
          acc[i][j] = __builtin_amdgcn_mfma_f32_16x16x32_bf16(af[i], bfr[j], acc[i][j], 0, 0, 0);
    }
  }

  // epilogue: D col = l&15, row = 4*(lane>>4) + reg
#pragma unroll
  for (int i = 0; i < 4; i++) {
    int rbase = row0 + wr + i * 16 + g * 4;
#pragma unroll
    for (int j = 0; j < 4; j++) {
      int col = col0 + wc + j * 16 + l15;
      f32x4 v = acc[i][j];
      if constexpr (MODE == 0) {
        int seg = col >> 10;
        int f   = col & 1023;                // head-major feature
        if (seg == 0) {
          int cl = permc(f);                 // phiq: [n][f_perm] (attn's k-dim)
#pragma unroll
          for (int rr = 0; rr < 4; rr++)
            o0[(size_t)(rbase + rr) * 1024 + cl] = (bf16_t)phi_fn(v[rr]);
        } else {
          // TRANSPOSED: [f][token_p6]; rbase 4-aligned => 4 contiguous tokens
          int tp = (rbase & ~63) | p6(rbase & 63);
          bf16x4 pack;
#pragma unroll
          for (int rr = 0; rr < 4; rr++)
            pack[rr] = (bf16_t)(seg == 1 ? phi_fn(v[rr]) : v[rr]);
          bf16_t* dst = (seg == 1) ? o1 : o2;
          *(bf16x4*)(dst + (size_t)f * 16384 + tp) = pack;
        }
      } else if constexpr (MODE == 1) {
        float bv = bias[col];
        int cs = permc(col);                 // FFN2's k-dim
#pragma unroll
        for (int rr = 0; rr < 4; rr++)
          o0[(size_t)(rbase + rr) * 1024 + cs] = (bf16_t)gelu_fn(v[rr] + bv);
      } else {
        float bv = bias[col];
#pragma unroll
        for (int rr = 0; rr < 4; rr++)
          o0[(size_t)(rbase + rr) * 1024 + col] = (bf16_t)(v[rr] + bv);
      }
    }
  }
}

// ---------------- kv_sum via MFMA (C[d][f] = sum_n phikT[d][n] * vT[f][n]) ---
// Same staging/fragment structure as gemm_bt; M=N=128, K-chunk = 256 tokens.
// Also folds the z partial sum (z[d] = sum_n phik[d][n]): threads tid<128 sum
// their As row per tile from LDS (bank-skewed granule order: 8-way not 32-way),
// writing Zp[h][c][d]. reduce_kvsum finishes both reductions. This replaces
// the separate 33-MB-read zsumT pass.

__global__ __launch_bounds__(256, 4)
void kvsum_mfma_kernel(const bf16_t* __restrict__ phikT, const bf16_t* __restrict__ vT,
                       float* __restrict__ P, float* __restrict__ Zp)
{
  __shared__ bf16_t As[128 * 64];
  __shared__ bf16_t Bs[128 * 64];
  const int h = blockIdx.y, c = blockIdx.x;
  const bf16_t* A = phikT + (size_t)h * 128 * 16384;
  const bf16_t* B = vT    + (size_t)h * 128 * 16384;
  const int tid = threadIdx.x, lane = tid & 63, wave = tid >> 6;
  const int wr = (wave >> 1) * 64, wc = (wave & 1) * 64;
  const int l15 = lane & 15, g = lane >> 4;
  const int cb = wave * 256;
  f32x4 acc[4][4] = {};
  float zacc = 0.f;

  for (int kk = 0; kk < 4; ++kk) {
    const int kt = c * 256 + kk * 64;
    __syncthreads();
#pragma unroll
    for (int it = 0; it < 4; ++it) {
      int ch = cb + it * 64 + lane;
      int r = ch >> 3;
      int csrc = (ch & 7) ^ (r & 7);
      gload16(A + (size_t)r * 16384 + kt + csrc * 8, As + (size_t)(cb + it * 64) * 8);
      gload16(B + (size_t)r * 16384 + kt + csrc * 8, Bs + (size_t)(cb + it * 64) * 8);
    }
    __syncthreads();
    if (tid < 128) {                         // z partial: row tid's 64 tokens (any order)
#pragma unroll
      for (int j = 0; j < 8; j++) {
        bf16x8 v8 = *(const bf16x8*)(As + tid * 64 + (((j + tid) & 7) * 8));
#pragma unroll
        for (int e = 0; e < 8; e++) zacc += (float)v8[e];
      }
    }
#pragma unroll
    for (int ks = 0; ks < 2; ++ks) {
      bf16x8 af[4], bfr[4];
#pragma unroll
      for (int i = 0; i < 4; i++) af[i]  = ldsf128(As, wr + i * 16 + l15, 128, ks * 64 + 16 * g);
#pragma unroll
      for (int i = 0; i < 4; i++) bfr[i] = ldsf128(Bs, wc + i * 16 + l15, 128, ks * 64 + 16 * g);
#pragma unroll
      for (int i = 0; i < 4; i++)
#pragma unroll
        for (int j = 0; j < 4; j++)
          acc[i][j] = __builtin_amdgcn_mfma_f32_16x16x32_bf16(af[i], bfr[j], acc[i][j], 0, 0, 0);
    }
  }

  float* pb = P + ((size_t)h * 64 + c) * 16384;
#pragma unroll
  for (int i = 0; i < 4; i++) {
    int e = wr + i * 16 + g * 4;
#pragma unroll
    for (int j = 0; j < 4; j++) {
      int f = wc + j * 16 + l15;
      f32x4 v = acc[i][j];
#pragma unroll
      for (int rr = 0; rr < 4; rr++)
        pb[(size_t)(e + rr) * 128 + f] = v[rr];
    }
  }
  if (tid < 128) Zp[((size_t)h * 64 + c) * 128 + tid] = zacc;
}

// Reduce 64 partials/head: Mbt[h][f][d_storage] = sum_c P[h][c][d][f];
// z[h*128+d] = sum_c Zp[h][c][d] (d logical head-major, matching attn's p6i read).
__global__ void reduce_kvsum_kernel(const float* __restrict__ P, const float* __restrict__ Zp,
                                    bf16_t* __restrict__ Mbt, float* __restrict__ z)
{
  int i = blockIdx.x * 256 + threadIdx.x;    // [0, 131072)
  int h = i >> 14, d = (i >> 7) & 127, f = i & 127;
  const float* p = P + (size_t)h * 64 * 16384 + (size_t)d * 128 + f;
  float s = 0.f;
#pragma unroll 8
  for (int c = 0; c < 64; ++c) s += p[(size_t)c * 16384];
  int ds = (d & 64) | p6(d & 63);
  Mbt[(size_t)h * 16384 + f * 128 + ds] = (bf16_t)s;
  if (i < 1024) {
    int hh = i >> 7, dd = i & 127;
    const float* q = Zp + (size_t)hh * 64 * 128 + dd;
    float sz = 0.f;
#pragma unroll 8
    for (int c = 0; c < 64; ++c) sz += q[c * 128];
    z[i] = sz;
  }
}

// ---------------- attention num/den/t ----------------

__global__ __launch_bounds__(256, 3)
void attn_t_kernel(const bf16_t* __restrict__ phiq, const bf16_t* __restrict__ Mbt,
                   const float* __restrict__ z, bf16_t* __restrict__ tout)
{
  __shared__ bf16_t As[64 * 128];   // phiq rows (storage order)
  __shared__ bf16_t Bs[128 * 128];  // Mbt[h] : [f][d_storage]
  __shared__ float  zs[128];        // z indexed by d_storage
  __shared__ float  dens[64];
  int h = blockIdx.y, row0 = blockIdx.x * 64;
  int tid = threadIdx.x, lane = tid & 63, wave = tid >> 6;
  int wr = (wave >> 1) * 32, wc = (wave & 1) * 64;
  int l15 = lane & 15, g = lane >> 4;

#pragma unroll
  for (int it = 0; it < 4; ++it) {          // A: 64x128 = 1024 chunks
    int ch = it * 256 + tid;
    int r = ch >> 4, c8 = ch & 15;
    int cs = c8 ^ (r & 7);
    *(bf16x8*)(As + r * 128 + cs * 8) = *(const bf16x8*)(phiq + (size_t)(row0 + r) * 1024 + h * 128 + c8 * 8);
  }
#pragma unroll
  for (int it = 0; it < 8; ++it) {          // B: 128x128 = 2048 chunks
    int ch = it * 256 + tid;
    int r = ch >> 4, c8 = ch & 15;
    int cs = c8 ^ (r & 7);
    *(bf16x8*)(Bs + r * 128 + cs * 8) = *(const bf16x8*)(Mbt + (size_t)h * 16384 + ch * 8);
  }
  if (tid < 128) zs[tid] = z[h * 128 + ((tid & 64) | p6i(tid & 63))];
  __syncthreads();

  f32x4 acc[2][4] = {};
#pragma unroll
  for (int ks = 0; ks < 4; ++ks) {
    bf16x8 af[2], bfr[4];
#pragma unroll
    for (int i = 0; i < 2; i++) af[i]  = ldsf128(As, wr + i * 16 + l15, 256, ks * 64 + 16 * g);
#pragma unroll
    for (int j = 0; j < 4; j++) bfr[j] = ldsf128(Bs, wc + j * 16 + l15, 256, ks * 64 + 16 * g);
#pragma unroll
    for (int i = 0; i < 2; i++)
#pragma unroll
      for (int j = 0; j < 4; j++)
        acc[i][j] = __builtin_amdgcn_mfma_f32_16x16x32_bf16(af[i], bfr[j], acc[i][j], 0, 0, 0);
  }

  if (tid < 64) {                            // den (storage-order dot, skewed, swizzle-aware)
    float s = 0.f;
    const char* p = (const char*)As + tid * 256;
    int sw = (tid & 7) << 4;
    for (int d0 = 0; d0 < 128; ++d0) {
      int d = (d0 + tid) & 127;
      bf16_t kv = *(const bf16_t*)(p + ((2 * d) ^ sw));
      s += (float)kv * zs[d];
    }
    dens[tid] = s;
  }
  __syncthreads();

#pragma unroll
  for (int i = 0; i < 2; i++) {
    int lr = wr + i * 16 + g * 4;
#pragma unroll
    for (int j = 0; j < 4; j++) {
      int col = h * 128 + wc + j * 16 + l15;  // logical head-major
      f32x4 v = acc[i][j];
#pragma unroll
      for (int rr = 0; rr < 4; rr++) {
        float den = dens[lr + rr] + 1e-6f;
        tout[(size_t)(row0 + lr + rr) * 1024 + col] = (bf16_t)(v[rr] / den);
      }
    }
  }
}

// ---------------- LayerNorms ----------------

// y = LN(unpermute(t) + x) * g + b   (y written PERM'd for FFN1's k-dim)
__global__ __launch_bounds__(256, 2)
void ln1_kernel(const bf16_t* __restrict__ t, const float* __restrict__ x,
                const float* __restrict__ gma, const float* __restrict__ bta,
                bf16_t* __restrict__ y)
{
  __shared__ float s[1024];
  __shared__ float rsum[4], rsq[4];
  int n = blockIdx.x, tid = threadIdx.x;
#pragma unroll
  for (int k = 0; k < 4; k++) {
    int p = k * 256 + tid;
    float tv = (float)t[(size_t)n * 1024 + p];
    int c = ((p & 127) << 3) | (p >> 7);     // head-major -> natural
    s[c] = tv;
  }
  __syncthreads();
  float sum = 0.f, sq = 0.f, sv[4];
#pragma unroll
  for (int k = 0; k < 4; k++) {
    int c = k * 256 + tid;
    float v = s[c] + x[(size_t)n * 1024 + c];
    sv[k] = v; sum += v; sq += v * v;
  }
#pragma unroll
  for (int o = 32; o > 0; o >>= 1) { sum += __shfl_down(sum, o); sq += __shfl_down(sq, o); }
  if ((tid & 63) == 0) { rsum[tid >> 6] = sum; rsq[tid >> 6] = sq; }
  __syncthreads();
  sum = rsum[0] + rsum[1] + rsum[2] + rsum[3];
  sq  = rsq[0] + rsq[1] + rsq[2] + rsq[3];
  float mu = sum * (1.f / 1024.f);
  float var = sq * (1.f / 1024.f) - mu * mu;
  float rs = rsqrtf(var + 1e-5f);
#pragma unroll
  for (int k = 0; k < 4; k++) {
    int c = k * 256 + tid;
    y[(size_t)n * 1024 + permc(c)] = (bf16_t)((sv[k] - mu) * rs * gma[c] + bta[c]);
  }
}

// out = LN(f + y) * g + b   (f natural; y stored PERM'd; out f32 natural)
__global__ __launch_bounds__(256, 2)
void ln2_kernel(const bf16_t* __restrict__ f, const bf16_t* __restrict__ y,
                const float* __restrict__ gma, const float* __restrict__ bta,
                float* __restrict__ out)
{
  __shared__ float rsum[4], rsq[4];
  int n = blockIdx.x, tid = threadIdx.x;
  float sum = 0.f, sq = 0.f, sv[4];
#pragma unroll
  for (int k = 0; k < 4; k++) {
    int c = k * 256 + tid;
    float v = (float)f[(size_t)n * 1024 + c] + (float)y[(size_t)n * 1024 + permc(c)];
    sv[k] = v; sum += v; sq += v * v;
  }
#pragma unroll
  for (int o = 32; o > 0; o >>= 1) { sum += __shfl_down(sum, o); sq += __shfl_down(sq, o); }
  if ((tid & 63) == 0) { rsum[tid >> 6] = sum; rsq[tid >> 6] = sq; }
  __syncthreads();
  sum = rsum[0] + rsum[1] + rsum[2] + rsum[3];
  sq  = rsq[0] + rsq[1] + rsq[2] + rsq[3];
  float mu = sum * (1.f / 1024.f);
  float var = sq * (1.f / 1024.f) - mu * mu;
  float rs = rsqrtf(var + 1e-5f);
#pragma unroll
  for (int k = 0; k < 4; k++) {
    int c = k * 256 + tid;
    out[(size_t)n * 1024 + c] = (sv[k] - mu) * rs * gma[c] + bta[c];
  }
}

// ---------------- launcher ----------------

extern "C" void kernel_launch(void* const* d_in, const int* in_sizes, int n_in,
                              void* d_out, int out_size, void* d_ws, size_t ws_size,
                              hipStream_t stream)
{
  const float* x    = (const float*)d_in[0];
  const float* Wq   = (const float*)d_in[1];
  const float* Wkv  = (const float*)d_in[2];
  const float* g1   = (const float*)d_in[3];
  const float* bt1  = (const float*)d_in[4];
  const float* W1   = (const float*)d_in[5];
  const float* b1   = (const float*)d_in[6];
  const float* W2   = (const float*)d_in[7];
  const float* b2   = (const float*)d_in[8];
  const float* g2   = (const float*)d_in[9];
  const float* bt2  = (const float*)d_in[10];
  float* out = (float*)d_out;

  char* ws = (char*)d_ws;
  size_t off = 0;
  auto alloc = [&](size_t bytes) { void* p = ws + off; off += (bytes + 255) & ~(size_t)255; return p; };

  const size_t NC2 = (size_t)NROWS * CDIM * 2;          // 33.5 MB (bf16)
  bf16_t* xb    = (bf16_t*)alloc(NC2);                  // xb; later: kvsum partials P; later: t
  bf16_t* wqkv  = (bf16_t*)alloc((size_t)3072 * 1024 * 2);
  bf16_t* w1bt  = (bf16_t*)alloc((size_t)1024 * 1024 * 2);
  bf16_t* w2bt  = (bf16_t*)alloc((size_t)1024 * 1024 * 2);
  bf16_t* phiq  = (bf16_t*)alloc(NC2);
  bf16_t* phikT = (bf16_t*)alloc(NC2);                  // [1024][16384]; later reused as h
  bf16_t* vT    = (bf16_t*)alloc(NC2);                  // [1024][16384]; later reused as f
  bf16_t* ybuf  = (bf16_t*)alloc(NC2);
  float*  Zp    = (float*)alloc(262144);                // Zp[8][64][128]
  float*  zbuf  = (float*)alloc(4096);                  // z[1024]
  bf16_t* Mbt   = (bf16_t*)alloc(262144);
  float*  Pbuf  = (float*)xb;                           // alias: 8*64*16384 f32 = exactly NC2 bytes
  bf16_t* tbuf  = xb;                                   // alias (P dead after reduce)
  bf16_t* hbuf  = phikT;                                // alias (phikT dead after kvsum)
  bf16_t* fbuf  = vT;                                   // alias (vT dead after kvsum)

  cast_x_kernel<<<2048, 256, 0, stream>>>(x, xb, (long)NROWS * CDIM / 8);
  prep_w_kernel<<<dim3(16, 16, 5), 256, 0, stream>>>(Wq, Wkv, W1, W2, wqkv, w1bt, w2bt);

  gemm_bt_kernel<0><<<dim3(128, 24), 256, 0, stream>>>(xb, wqkv, nullptr, phiq, phikT, vT,
                                                       NROWS, 3072, 1024);
  kvsum_mfma_kernel<<<dim3(64, 8), 256, 0, stream>>>(phikT, vT, Pbuf, Zp);
  reduce_kvsum_kernel<<<512, 256, 0, stream>>>(Pbuf, Zp, Mbt, zbuf);
  attn_t_kernel<<<dim3(256, 8), 256, 0, stream>>>(phiq, Mbt, zbuf, tbuf);
  ln1_kernel<<<NROWS, 256, 0, stream>>>(tbuf, x, g1, bt1, ybuf);

  gemm_bt_kernel<1><<<dim3(128, 8), 256, 0, stream>>>(ybuf, w1bt, b1, hbuf, nullptr, nullptr,
                                                      NROWS, 1024, 1024);
  gemm_bt_kernel<2><<<dim3(128, 8), 256, 0, stream>>>(hbuf, w2bt, b2, fbuf, nullptr, nullptr,
                                                      NROWS, 1024, 1024);
  ln2_kernel<<<NROWS, 256, 0, stream>>>(fbuf, ybuf, g2, bt2, out);
}

// Round 14
// 306.896 us; speedup vs baseline: 1.2108x; 1.0215x over previous
//
#include <hip/hip_runtime.h>
#include <hip/hip_bf16.h>
#include <cstdint>
#include <cstddef>

typedef __bf16 bf16_t;
typedef bf16_t bf16x4 __attribute__((ext_vector_type(4)));
typedef bf16_t bf16x8 __attribute__((ext_vector_type(8)));
typedef float f32x4 __attribute__((ext_vector_type(4)));

static constexpr int NROWS = 16384;
static constexpr int CDIM  = 1024;

// ---------------- K-permutation (contiguous MFMA fragments) ----------------
// p6: k=[b5 b4 b3 b2 b1 b0] -> s=[b5 b3 b2 b4 b1 b0]; maps {0..31}->{0..31};
// preserves k&3, so 4-aligned groups stay 4-contiguous.
__device__ __forceinline__ int p6(int k) {
  return (k & 32) | ((k & 12) << 1) | ((k & 16) >> 2) | (k & 3);
}
__device__ __forceinline__ int p6i(int s) {
  return (s & 32) | ((s & 4) << 2) | ((s & 24) >> 1) | (s & 3);
}
__device__ __forceinline__ int permc(int c) {        // within-64 perm of a wider index
  return (c & ~63) | p6(c & 63);
}

// ---------------- helpers ----------------

__device__ __forceinline__ void gload16(const bf16_t* g, bf16_t* l) {
  __builtin_amdgcn_global_load_lds((const __attribute__((address_space(1))) void*)g,
                                   (__attribute__((address_space(3))) void*)l, 16, 0, 0);
}

// Single-b128 fragment load from a row-major LDS tile whose 16B granules are
// XOR-swizzled: granule byte-addr ^= (row&7)<<4. kbyte is a multiple of 16.
__device__ __forceinline__ bf16x8 ldsf128(const bf16_t* lds, int row, int ldbytes, int kbyte) {
  const char* p = (const char*)lds + row * ldbytes + (kbyte ^ ((row & 7) << 4));
  return *(const bf16x8*)p;
}

__device__ __forceinline__ float phi_fn(float v) {           // elu + 1
  return v > 0.f ? v + 1.f : expf(v);
}
__device__ __forceinline__ float gelu_fn(float v) {          // exact gelu
  return 0.5f * v * (1.f + erff(v * 0.70710678118654752f));
}

// ---------------- elementwise / prep ----------------

// xb[row][PERM(c)] = (bf16) x[row][c]  -- written chunk-wise (8 elems/chunk).
__global__ void cast_x_kernel(const float* __restrict__ x, bf16_t* __restrict__ xb, long nchunks) {
  long i = (long)blockIdx.x * blockDim.x + threadIdx.x;
  long stride = (long)gridDim.x * blockDim.x;
  for (long c = i; c < nchunks; c += stride) {
    long row = c >> 7;
    int p0 = (int)(c & 127) << 3;            // storage position of this 8-elem chunk
    int group = p0 & ~63;
    int ccl = (p0 >> 3) & 7;                 // chunk within 64-group
    int klo = ((ccl & 4) << 3) | ((ccl & 3) << 2);   // logical k of elems 0-3 (4-7 = +16)
    const float* src = x + row * 1024 + group + klo;
    float4 a = *(const float4*)src;
    float4 b = *(const float4*)(src + 16);
    bf16x8 o;
    o[0] = (bf16_t)a.x; o[1] = (bf16_t)a.y; o[2] = (bf16_t)a.z; o[3] = (bf16_t)a.w;
    o[4] = (bf16_t)b.x; o[5] = (bf16_t)b.y; o[6] = (bf16_t)b.z; o[7] = (bf16_t)b.w;
    *(bf16x8*)(xb + row * 1024 + p0) = o;
  }
}

// Transpose-cast weights to column-major bf16 (Bt[n][k_perm]); modes 0-2 also
// apply the head-major column permutation perm(c) = (c%8)*128 + c/8.
__global__ void prep_w_kernel(const float* __restrict__ Wq, const float* __restrict__ Wkv,
                              const float* __restrict__ W1, const float* __restrict__ W2,
                              bf16_t* __restrict__ wqkv_bt, bf16_t* __restrict__ w1bt,
                              bf16_t* __restrict__ w2bt) {
  __shared__ float tile[64][65];
  int mode = blockIdx.z;
  const float* src; int ld; bf16_t* dst; int permute;
  if (mode == 0)      { src = Wq;          ld = 1024; dst = wqkv_bt;                       permute = 1; }
  else if (mode == 1) { src = Wkv;         ld = 2048; dst = wqkv_bt + (size_t)1024 * 1024; permute = 1; }
  else if (mode == 2) { src = Wkv + 1024;  ld = 2048; dst = wqkv_bt + (size_t)2048 * 1024; permute = 1; }
  else if (mode == 3) { src = W1;          ld = 1024; dst = w1bt;                          permute = 0; }
  else                { src = W2;          ld = 1024; dst = w2bt;                          permute = 0; }
  int r0 = blockIdx.x * 64, c0 = blockIdx.y * 64;
  int tid = threadIdx.x;
#pragma unroll
  for (int i = 0; i < 16; i++) {
    int idx = i * 256 + tid; int rr = idx >> 6, cc = idx & 63;
    tile[rr][cc] = src[(size_t)(r0 + rr) * ld + c0 + cc];
  }
  __syncthreads();
#pragma unroll
  for (int i = 0; i < 16; i++) {
    int idx = i * 256 + tid; int cc = idx >> 6, rr = idx & 63;
    int c = c0 + cc;
    int a = permute ? (((c & 7) << 7) | (c >> 3)) : c;
    dst[(size_t)a * 1024 + r0 + p6(rr)] = (bf16_t)tile[rr][cc];
  }
}

// ---------------- main GEMM (128x128, gload_lds, b128 frags) ----------------
// out = A[M][Kp] @ Bt[N][Kp]^T. LDS dest linear, source granule pre-XOR'd,
// fragment reads via swizzled ldsf128 (single ds_read_b128, conflict-free).
// Natural 2D dispatch is already XCD-optimal (R12's explicit swizzle hurt).
// MODE 0: QKV (N=3072): seg0 phi->phiq[n][permc(f)];
//         seg1 phi->phikT[f][token_p6]; seg2 v->vT[f][token_p6]  (TRANSPOSED)
// MODE 1: FFN1: gelu(acc+bias) -> o0 at PERM'd col
// MODE 2: FFN2: acc+bias -> o0 natural

template<int MODE>
__global__ __launch_bounds__(256, 4)
void gemm_bt_kernel(const bf16_t* __restrict__ A, const bf16_t* __restrict__ Bt,
                    const float* __restrict__ bias,
                    bf16_t* __restrict__ o0, bf16_t* __restrict__ o1, bf16_t* __restrict__ o2,
                    int M, int N, int K)
{
  __shared__ bf16_t As[128 * 64];
  __shared__ bf16_t Bs[128 * 64];
  const int tid  = threadIdx.x;
  const int lane = tid & 63;
  const int wave = tid >> 6;
  const int wr = (wave >> 1) * 64, wc = (wave & 1) * 64;
  const int l15 = lane & 15, g = lane >> 4;
  const int row0 = blockIdx.x * 128, col0 = blockIdx.y * 128;
  const int cb = wave * 256;                 // this wave's 256-chunk slice of 1024
  f32x4 acc[4][4] = {};

  for (int kt = 0; kt < K; kt += 64) {
    __syncthreads();                         // prior iter's LDS reads done
#pragma unroll
    for (int it = 0; it < 4; ++it) {
      int ch = cb + it * 64 + lane;          // LDS 16B-chunk id (linear dest)
      int r = ch >> 3;
      int csrc = (ch & 7) ^ (r & 7);         // inverse-swizzled source granule
      gload16(A  + (size_t)(row0 + r) * K + kt + csrc * 8, As + (size_t)(cb + it * 64) * 8);
      gload16(Bt + (size_t)(col0 + r) * K + kt + csrc * 8, Bs + (size_t)(cb + it * 64) * 8);
    }
    __syncthreads();
#pragma unroll
    for (int ks = 0; ks < 2; ++ks) {
      bf16x8 af[4], bfr[4];
#pragma unroll
      for (int i = 0; i < 4; i++) af[i]  = ldsf128(As, wr + i * 16 + l15, 128, ks * 64 + 16 * g);
#pragma unroll
      for (int i = 0; i < 4; i++) bfr[i] = ldsf128(Bs, wc + i * 16 + l15, 128, ks * 64 + 16 * g);
#pragma unroll
      for (int i = 0; i < 4; i++)
#pragma unroll
        for (int j = 0; j < 4; j++)
          acc[i][j] = __builtin_amdgcn_mfma_f32_16x16x32_bf16(af[i], bfr[j], acc[i][j], 0, 0, 0);
    }
  }

  // epilogue: D col = l&15, row = 4*(lane>>4) + reg
#pragma unroll
  for (int i = 0; i < 4; i++) {
    int rbase = row0 + wr + i * 16 + g * 4;
#pragma unroll
    for (int j = 0; j < 4; j++) {
      int col = col0 + wc + j * 16 + l15;
      f32x4 v = acc[i][j];
      if constexpr (MODE == 0) {
        int seg = col >> 10;
        int f   = col & 1023;                // head-major feature
        if (seg == 0) {
          int cl = permc(f);                 // phiq: [n][f_perm] (attn's k-dim)
#pragma unroll
          for (int rr = 0; rr < 4; rr++)
            o0[(size_t)(rbase + rr) * 1024 + cl] = (bf16_t)phi_fn(v[rr]);
        } else {
          // TRANSPOSED: [f][token_p6]; rbase 4-aligned => 4 contiguous tokens
          int tp = (rbase & ~63) | p6(rbase & 63);
          bf16x4 pack;
#pragma unroll
          for (int rr = 0; rr < 4; rr++)
            pack[rr] = (bf16_t)(seg == 1 ? phi_fn(v[rr]) : v[rr]);
          bf16_t* dst = (seg == 1) ? o1 : o2;
          *(bf16x4*)(dst + (size_t)f * 16384 + tp) = pack;
        }
      } else if constexpr (MODE == 1) {
        float bv = bias[col];
        int cs = permc(col);                 // FFN2's k-dim
#pragma unroll
        for (int rr = 0; rr < 4; rr++)
          o0[(size_t)(rbase + rr) * 1024 + cs] = (bf16_t)gelu_fn(v[rr] + bv);
      } else {
        float bv = bias[col];
#pragma unroll
        for (int rr = 0; rr < 4; rr++)
          o0[(size_t)(rbase + rr) * 1024 + col] = (bf16_t)(v[rr] + bv);
      }
    }
  }
}

// ---------------- kv_sum via MFMA (C[d][f] = sum_n phikT[d][n] * vT[f][n]) ---
// 32 chunks x 8 heads, 512 tokens/chunk (halves partial traffic vs 64 chunks).
// Also folds the z partial sum from the staged As tile (bank-skewed reads).

__global__ __launch_bounds__(256, 4)
void kvsum_mfma_kernel(const bf16_t* __restrict__ phikT, const bf16_t* __restrict__ vT,
                       float* __restrict__ P, float* __restrict__ Zp)
{
  __shared__ bf16_t As[128 * 64];
  __shared__ bf16_t Bs[128 * 64];
  const int h = blockIdx.y, c = blockIdx.x;
  const bf16_t* A = phikT + (size_t)h * 128 * 16384;
  const bf16_t* B = vT    + (size_t)h * 128 * 16384;
  const int tid = threadIdx.x, lane = tid & 63, wave = tid >> 6;
  const int wr = (wave >> 1) * 64, wc = (wave & 1) * 64;
  const int l15 = lane & 15, g = lane >> 4;
  const int cb = wave * 256;
  f32x4 acc[4][4] = {};
  float zacc = 0.f;

  for (int kk = 0; kk < 8; ++kk) {
    const int kt = c * 512 + kk * 64;
    __syncthreads();
#pragma unroll
    for (int it = 0; it < 4; ++it) {
      int ch = cb + it * 64 + lane;
      int r = ch >> 3;
      int csrc = (ch & 7) ^ (r & 7);
      gload16(A + (size_t)r * 16384 + kt + csrc * 8, As + (size_t)(cb + it * 64) * 8);
      gload16(B + (size_t)r * 16384 + kt + csrc * 8, Bs + (size_t)(cb + it * 64) * 8);
    }
    __syncthreads();
    if (tid < 128) {                         // z partial: row tid's 64 tokens (any order)
#pragma unroll
      for (int j = 0; j < 8; j++) {
        bf16x8 v8 = *(const bf16x8*)(As + tid * 64 + (((j + tid) & 7) * 8));
#pragma unroll
        for (int e = 0; e < 8; e++) zacc += (float)v8[e];
      }
    }
#pragma unroll
    for (int ks = 0; ks < 2; ++ks) {
      bf16x8 af[4], bfr[4];
#pragma unroll
      for (int i = 0; i < 4; i++) af[i]  = ldsf128(As, wr + i * 16 + l15, 128, ks * 64 + 16 * g);
#pragma unroll
      for (int i = 0; i < 4; i++) bfr[i] = ldsf128(Bs, wc + i * 16 + l15, 128, ks * 64 + 16 * g);
#pragma unroll
      for (int i = 0; i < 4; i++)
#pragma unroll
        for (int j = 0; j < 4; j++)
          acc[i][j] = __builtin_amdgcn_mfma_f32_16x16x32_bf16(af[i], bfr[j], acc[i][j], 0, 0, 0);
    }
  }

  float* pb = P + ((size_t)h * 32 + c) * 16384;
#pragma unroll
  for (int i = 0; i < 4; i++) {
    int e = wr + i * 16 + g * 4;
#pragma unroll
    for (int j = 0; j < 4; j++) {
      int f = wc + j * 16 + l15;
      f32x4 v = acc[i][j];
#pragma unroll
      for (int rr = 0; rr < 4; rr++)
        pb[(size_t)(e + rr) * 128 + f] = v[rr];
    }
  }
  if (tid < 128) Zp[((size_t)h * 32 + c) * 128 + tid] = zacc;
}

// Reduce 32 partials/head: Mbt[h][f][d_storage] = sum_c P[h][c][d][f];
// z[h*128+d] = sum_c Zp[h][c][d] (d logical head-major; attn reads via p6i).
__global__ void reduce_kvsum_kernel(const float* __restrict__ P, const float* __restrict__ Zp,
                                    bf16_t* __restrict__ Mbt, float* __restrict__ z)
{
  int i = blockIdx.x * 256 + threadIdx.x;    // [0, 131072)
  int h = i >> 14, d = (i >> 7) & 127, f = i & 127;
  const float* p = P + (size_t)h * 32 * 16384 + (size_t)d * 128 + f;
  float s = 0.f;
#pragma unroll 8
  for (int c = 0; c < 32; ++c) s += p[(size_t)c * 16384];
  int ds = (d & 64) | p6(d & 63);
  Mbt[(size_t)h * 16384 + f * 128 + ds] = (bf16_t)s;
  if (i < 1024) {
    int hh = i >> 7, dd = i & 127;
    const float* q = Zp + (size_t)hh * 32 * 128 + dd;
    float sz = 0.f;
#pragma unroll 8
    for (int c = 0; c < 32; ++c) sz += q[c * 128];
    z[i] = sz;
  }
}

// ---------------- attention num/den/t ----------------

__global__ __launch_bounds__(256, 3)
void attn_t_kernel(const bf16_t* __restrict__ phiq, const bf16_t* __restrict__ Mbt,
                   const float* __restrict__ z, bf16_t* __restrict__ tout)
{
  __shared__ bf16_t As[64 * 128];   // phiq rows (storage order)
  __shared__ bf16_t Bs[128 * 128];  // Mbt[h] : [f][d_storage]
  __shared__ float  zs[128];        // z indexed by d_storage
  __shared__ float  dens[64];
  int h = blockIdx.y, row0 = blockIdx.x * 64;
  int tid = threadIdx.x, lane = tid & 63, wave = tid >> 6;
  int wr = (wave >> 1) * 32, wc = (wave & 1) * 64;
  int l15 = lane & 15, g = lane >> 4;

#pragma unroll
  for (int it = 0; it < 4; ++it) {          // A: 64x128 = 1024 chunks
    int ch = it * 256 + tid;
    int r = ch >> 4, c8 = ch & 15;
    int cs = c8 ^ (r & 7);
    *(bf16x8*)(As + r * 128 + cs * 8) = *(const bf16x8*)(phiq + (size_t)(row0 + r) * 1024 + h * 128 + c8 * 8);
  }
#pragma unroll
  for (int it = 0; it < 8; ++it) {          // B: 128x128 = 2048 chunks
    int ch = it * 256 + tid;
    int r = ch >> 4, c8 = ch & 15;
    int cs = c8 ^ (r & 7);
    *(bf16x8*)(Bs + r * 128 + cs * 8) = *(const bf16x8*)(Mbt + (size_t)h * 16384 + ch * 8);
  }
  if (tid < 128) zs[tid] = z[h * 128 + ((tid & 64) | p6i(tid & 63))];
  __syncthreads();

  f32x4 acc[2][4] = {};
#pragma unroll
  for (int ks = 0; ks < 4; ++ks) {
    bf16x8 af[2], bfr[4];
#pragma unroll
    for (int i = 0; i < 2; i++) af[i]  = ldsf128(As, wr + i * 16 + l15, 256, ks * 64 + 16 * g);
#pragma unroll
    for (int j = 0; j < 4; j++) bfr[j] = ldsf128(Bs, wc + j * 16 + l15, 256, ks * 64 + 16 * g);
#pragma unroll
    for (int i = 0; i < 2; i++)
#pragma unroll
      for (int j = 0; j < 4; j++)
        acc[i][j] = __builtin_amdgcn_mfma_f32_16x16x32_bf16(af[i], bfr[j], acc[i][j], 0, 0, 0);
  }

  // den: all 256 threads; row r = tid>>2, quarter q = tid&3 (4 granules each),
  // quad shfl-reduce. Replaces the 1-wave 128-iter serial loop.
  {
    int r = tid >> 2, q = tid & 3;
    const char* p = (const char*)As + r * 256;
    int sw = (r & 7) << 4;
    float s = 0.f;
#pragma unroll
    for (int j = 0; j < 4; j++) {
      int gi = q * 4 + j;                    // granule id; elems gi*8..+7
      bf16x8 v8 = *(const bf16x8*)(p + ((gi * 16) ^ sw));
#pragma unroll
      for (int e = 0; e < 8; e++) s += (float)v8[e] * zs[gi * 8 + e];
    }
    s += __shfl_xor(s, 1);
    s += __shfl_xor(s, 2);
    if (q == 0) dens[r] = s;
  }
  __syncthreads();

#pragma unroll
  for (int i = 0; i < 2; i++) {
    int lr = wr + i * 16 + g * 4;
#pragma unroll
    for (int j = 0; j < 4; j++) {
      int col = h * 128 + wc + j * 16 + l15;  // logical head-major
      f32x4 v = acc[i][j];
#pragma unroll
      for (int rr = 0; rr < 4; rr++) {
        float den = dens[lr + rr] + 1e-6f;
        tout[(size_t)(row0 + lr + rr) * 1024 + col] = (bf16_t)(v[rr] / den);
      }
    }
  }
}

// ---------------- LayerNorms ----------------

// y = LN(unpermute(t) + xb) * g + b   (xb = bf16 permuted x; y written PERM'd)
__global__ __launch_bounds__(256, 2)
void ln1_kernel(const bf16_t* __restrict__ t, const bf16_t* __restrict__ xb,
                const float* __restrict__ gma, const float* __restrict__ bta,
                bf16_t* __restrict__ y)
{
  __shared__ float s[1024];
  __shared__ float rsum[4], rsq[4];
  int n = blockIdx.x, tid = threadIdx.x;
#pragma unroll
  for (int k = 0; k < 4; k++) {
    int p = k * 256 + tid;
    float tv = (float)t[(size_t)n * 1024 + p];
    int c = ((p & 127) << 3) | (p >> 7);     // head-major -> natural
    s[c] = tv;
  }
  __syncthreads();
  float sum = 0.f, sq = 0.f, sv[4];
#pragma unroll
  for (int k = 0; k < 4; k++) {
    int c = k * 256 + tid;
    float v = s[c] + (float)xb[(size_t)n * 1024 + permc(c)];
    sv[k] = v; sum += v; sq += v * v;
  }
#pragma unroll
  for (int o = 32; o > 0; o >>= 1) { sum += __shfl_down(sum, o); sq += __shfl_down(sq, o); }
  if ((tid & 63) == 0) { rsum[tid >> 6] = sum; rsq[tid >> 6] = sq; }
  __syncthreads();
  sum = rsum[0] + rsum[1] + rsum[2] + rsum[3];
  sq  = rsq[0] + rsq[1] + rsq[2] + rsq[3];
  float mu = sum * (1.f / 1024.f);
  float var = sq * (1.f / 1024.f) - mu * mu;
  float rs = rsqrtf(var + 1e-5f);
#pragma unroll
  for (int k = 0; k < 4; k++) {
    int c = k * 256 + tid;
    y[(size_t)n * 1024 + permc(c)] = (bf16_t)((sv[k] - mu) * rs * gma[c] + bta[c]);
  }
}

// out = LN(f + y) * g + b   (f natural; y stored PERM'd; out f32 natural)
__global__ __launch_bounds__(256, 2)
void ln2_kernel(const bf16_t* __restrict__ f, const bf16_t* __restrict__ y,
                const float* __restrict__ gma, const float* __restrict__ bta,
                float* __restrict__ out)
{
  __shared__ float rsum[4], rsq[4];
  int n = blockIdx.x, tid = threadIdx.x;
  float sum = 0.f, sq = 0.f, sv[4];
#pragma unroll
  for (int k = 0; k < 4; k++) {
    int c = k * 256 + tid;
    float v = (float)f[(size_t)n * 1024 + c] + (float)y[(size_t)n * 1024 + permc(c)];
    sv[k] = v; sum += v; sq += v * v;
  }
#pragma unroll
  for (int o = 32; o > 0; o >>= 1) { sum += __shfl_down(sum, o); sq += __shfl_down(sq, o); }
  if ((tid & 63) == 0) { rsum[tid >> 6] = sum; rsq[tid >> 6] = sq; }
  __syncthreads();
  sum = rsum[0] + rsum[1] + rsum[2] + rsum[3];
  sq  = rsq[0] + rsq[1] + rsq[2] + rsq[3];
  float mu = sum * (1.f / 1024.f);
  float var = sq * (1.f / 1024.f) - mu * mu;
  float rs = rsqrtf(var + 1e-5f);
#pragma unroll
  for (int k = 0; k < 4; k++) {
    int c = k * 256 + tid;
    out[(size_t)n * 1024 + c] = (sv[k] - mu) * rs * gma[c] + bta[c];
  }
}

// ---------------- launcher ----------------

extern "C" void kernel_launch(void* const* d_in, const int* in_sizes, int n_in,
                              void* d_out, int out_size, void* d_ws, size_t ws_size,
                              hipStream_t stream)
{
  const float* x    = (const float*)d_in[0];
  const float* Wq   = (const float*)d_in[1];
  const float* Wkv  = (const float*)d_in[2];
  const float* g1   = (const float*)d_in[3];
  const float* bt1  = (const float*)d_in[4];
  const float* W1   = (const float*)d_in[5];
  const float* b1   = (const float*)d_in[6];
  const float* W2   = (const float*)d_in[7];
  const float* b2   = (const float*)d_in[8];
  const float* g2   = (const float*)d_in[9];
  const float* bt2  = (const float*)d_in[10];
  float* out = (float*)d_out;

  char* ws = (char*)d_ws;
  size_t off = 0;
  auto alloc = [&](size_t bytes) { void* p = ws + off; off += (bytes + 255) & ~(size_t)255; return p; };

  const size_t NC2 = (size_t)NROWS * CDIM * 2;          // 33.5 MB (bf16)
  bf16_t* xb    = (bf16_t*)alloc(NC2);                  // bf16 permuted x (intact thru LN1)
  bf16_t* wqkv  = (bf16_t*)alloc((size_t)3072 * 1024 * 2);
  bf16_t* w1bt  = (bf16_t*)alloc((size_t)1024 * 1024 * 2);
  bf16_t* w2bt  = (bf16_t*)alloc((size_t)1024 * 1024 * 2);
  bf16_t* phiq  = (bf16_t*)alloc(NC2);
  bf16_t* phikT = (bf16_t*)alloc(NC2);                  // [1024][16384]; later: t, then h
  bf16_t* vT    = (bf16_t*)alloc(NC2);                  // [1024][16384]; later: f
  bf16_t* ybuf  = (bf16_t*)alloc(NC2);                  // early: kvsum partials P (16MB)
  float*  Zp    = (float*)alloc(262144);                // Zp[8][32][128] (128KB used)
  float*  zbuf  = (float*)alloc(4096);                  // z[1024]
  bf16_t* Mbt   = (bf16_t*)alloc(262144);
  float*  Pbuf  = (float*)ybuf;                         // alias: P dead before LN1 writes y
  bf16_t* tbuf  = phikT;                                // alias: phikT dead after kvsum
  bf16_t* hbuf  = phikT;                                // alias: t dead after LN1
  bf16_t* fbuf  = vT;                                   // alias: vT dead after kvsum

  cast_x_kernel<<<2048, 256, 0, stream>>>(x, xb, (long)NROWS * CDIM / 8);
  prep_w_kernel<<<dim3(16, 16, 5), 256, 0, stream>>>(Wq, Wkv, W1, W2, wqkv, w1bt, w2bt);

  gemm_bt_kernel<0><<<dim3(128, 24), 256, 0, stream>>>(xb, wqkv, nullptr, phiq, phikT, vT,
                                                       NROWS, 3072, 1024);
  kvsum_mfma_kernel<<<dim3(32, 8), 256, 0, stream>>>(phikT, vT, Pbuf, Zp);
  reduce_kvsum_kernel<<<512, 256, 0, stream>>>(Pbuf, Zp, Mbt, zbuf);
  attn_t_kernel<<<dim3(256, 8), 256, 0, stream>>>(phiq, Mbt, zbuf, tbuf);
  ln1_kernel<<<NROWS, 256, 0, stream>>>(tbuf, xb, g1, bt1, ybuf);

  gemm_bt_kernel<1><<<dim3(128, 8), 256, 0, stream>>>(ybuf, w1bt, b1, hbuf, nullptr, nullptr,
                                                      NROWS, 1024, 1024);
  gemm_bt_kernel<2><<<dim3(128, 8), 256, 0, stream>>>(hbuf, w2bt, b2, fbuf, nullptr, nullptr,
                                                      NROWS, 1024, 1024);
  ln2_kernel<<<NROWS, 256, 0, stream>>>(fbuf, ybuf, g2, bt2, out);
}